// Round 13
// baseline (2127.836 us; speedup 1.0000x reference)
//
#include <hip/hip_runtime.h>

#define D_MODEL 1024
#define SEQ     1024
#define BATCH   4
#define NHEAD   16
#define HDIM    64
#define FF_DIM  4096
#define NLAYER  8
#define VOCAB   32000
#define ROWS    (BATCH*SEQ)
#define QKV_N   3072
#define LN_EPS  1e-5f

typedef __attribute__((ext_vector_type(4))) float   f32x4;
typedef __attribute__((ext_vector_type(8))) unsigned short u16x8;
typedef __attribute__((ext_vector_type(8))) __bf16  bf16x8;

typedef const unsigned int __attribute__((address_space(1)))* gas_t;
typedef unsigned int __attribute__((address_space(3)))* las_t;

__device__ __forceinline__ void gld16(const void* g, void* l) {
    __builtin_amdgcn_global_load_lds((gas_t)g, (las_t)l, 16, 0, 0);
}

__device__ __forceinline__ unsigned short f2bf(float f) {
    unsigned int u = __builtin_bit_cast(unsigned int, f);
    u += 0x7FFFu + ((u >> 16) & 1u);   // RNE
    return (unsigned short)(u >> 16);
}

__device__ __forceinline__ float bf2f(unsigned short u) {
    return __builtin_bit_cast(float, (unsigned int)u << 16);
}

__device__ __forceinline__ f32x4 mfma32(u16x8 a, u16x8 b, f32x4 c) {
    return __builtin_amdgcn_mfma_f32_16x16x32_bf16(
        __builtin_bit_cast(bf16x8, a), __builtin_bit_cast(bf16x8, b), c, 0, 0, 0);
}

// ---------------- embed: xb = bf16(emb[tok] + pos) ----------------
__global__ __launch_bounds__(256) void embed_k(
    const int* __restrict__ tok, const float* __restrict__ emb,
    const float* __restrict__ pos, unsigned short* __restrict__ xb)
{
    int bs = blockIdx.x;
    int s  = bs & (SEQ - 1);
    int tk = tok[bs];
    int c  = threadIdx.x * 4;
    float4 e = *(const float4*)(emb + (size_t)tk * D_MODEL + c);
    float4 p = *(const float4*)(pos + (size_t)s * D_MODEL + c);
    float y0 = e.x + p.x, y1 = e.y + p.y, y2 = e.z + p.z, y3 = e.w + p.w;
    size_t base = (size_t)bs * D_MODEL + c;
    unsigned long long pk = (unsigned long long)f2bf(y0)
        | ((unsigned long long)f2bf(y1) << 16)
        | ((unsigned long long)f2bf(y2) << 32)
        | ((unsigned long long)f2bf(y3) << 48);
    *(unsigned long long*)(xb + base) = pk;
}

// ---------------- cast fp32 -> bf16 ----------------
__global__ __launch_bounds__(256) void cast_bf(
    const float* __restrict__ in, unsigned short* __restrict__ out, size_t n)
{
    size_t i = ((size_t)blockIdx.x * 256 + threadIdx.x) * 4;
    if (i >= n) return;
    float4 v = *(const float4*)(in + i);
    unsigned long long pk = (unsigned long long)f2bf(v.x)
        | ((unsigned long long)f2bf(v.y) << 16)
        | ((unsigned long long)f2bf(v.z) << 32)
        | ((unsigned long long)f2bf(v.w) << 48);
    *(unsigned long long*)(out + i) = pk;
}

// ---------------- concat qkv biases ----------------
__global__ __launch_bounds__(256) void bias3_k(
    const float* __restrict__ bq, const float* __restrict__ bk,
    const float* __restrict__ bv, float* __restrict__ out)
{
    int l = blockIdx.x / 3, which = blockIdx.x % 3;
    const float* src = which == 0 ? bq : (which == 1 ? bk : bv);
    int i = threadIdx.x * 4;
    float4 v = *(const float4*)(src + (size_t)l * D_MODEL + i);
    *(float4*)(out + (size_t)l * QKV_N + which * D_MODEL + i) = v;
}

// ---------------- transpose tile body (shared) ----------------
__device__ __forceinline__ void tc_tile(
    const float* __restrict__ W, unsigned short* __restrict__ Wt,
    int K, int N, int n0, int k0)
{
    __shared__ float t[64][65];
    int rr = threadIdx.x >> 4;          // 0..15
    int cc = (threadIdx.x & 15) * 4;    // 0..60
#pragma unroll
    for (int it = 0; it < 4; it++) {
        int r = it * 16 + rr;
        float4 v = *(const float4*)(W + (size_t)(k0 + r) * N + n0 + cc);
        t[r][cc] = v.x; t[r][cc + 1] = v.y; t[r][cc + 2] = v.z; t[r][cc + 3] = v.w;
    }
    __syncthreads();
#pragma unroll
    for (int it = 0; it < 4; it++) {
        int n = it * 16 + rr;
        unsigned long long pk = (unsigned long long)f2bf(t[cc][n])
            | ((unsigned long long)f2bf(t[cc + 1][n]) << 16)
            | ((unsigned long long)f2bf(t[cc + 2][n]) << 32)
            | ((unsigned long long)f2bf(t[cc + 3][n]) << 48);
        *(unsigned long long*)(Wt + (size_t)(n0 + n) * K + k0 + cc) = pk;
    }
}

// ---------------- per-tile transpose kernels (fallback path) ----------------
__global__ __launch_bounds__(256) void transpose_cast(
    const float* __restrict__ W, unsigned short* __restrict__ Wt, int K, int N)
{
    tc_tile(W, Wt, K, N, blockIdx.x * 64, blockIdx.y * 64);
}

__global__ __launch_bounds__(256) void transpose_cast3(
    const float* __restrict__ Wq, const float* __restrict__ Wk,
    const float* __restrict__ Wv, unsigned short* __restrict__ Wt)
{
    const int which = blockIdx.z;
    const float* W = which == 0 ? Wq : (which == 1 ? Wk : Wv);
    tc_tile(W, Wt + (size_t)which * (1024 * 1024), 1024, 1024,
            blockIdx.x * 64, blockIdx.y * 64);
}

// ---------------- per-layer fused transpose (fallback) ----------------
__global__ __launch_bounds__(256) void transpose_all(
    const float* __restrict__ Wq, const float* __restrict__ Wk,
    const float* __restrict__ Wv, const float* __restrict__ Wo,
    const float* __restrict__ W1, const float* __restrict__ W2,
    unsigned short* __restrict__ wt)
{
    int b = blockIdx.x;
    const float* W; unsigned short* out; int K, N, t;
    if (b < 768)       { int w = b >> 8; t = b & 255; W = w == 0 ? Wq : (w == 1 ? Wk : Wv);
                         out = wt + (size_t)w * 1048576; K = 1024; N = 1024; }
    else if (b < 1024) { t = b - 768;  W = Wo; out = wt + (size_t)3 * 1048576; K = 1024; N = 1024; }
    else if (b < 2048) { t = b - 1024; W = W1; out = wt + (size_t)4 * 1048576; K = 1024; N = 4096; }
    else               { t = b - 2048; W = W2; out = wt + (size_t)8 * 1048576; K = 4096; N = 1024; }
    int ntx = N >> 6;
    tc_tile(W, out, K, N, (t % ntx) * 64, (t / ntx) * 64);
}

// ---- ALL layers, all 6 weights, ONE launch: 8 x 3072 = 24576 blocks ----
// wtall layout per layer l (elems, stride 12M): [0,3M) qkv^T, [3M,4M) Wo^T,
// [4M,8M) W1^T, [8M,12M) W2^T
__global__ __launch_bounds__(256) void transpose_all_L(
    const float* __restrict__ Wq, const float* __restrict__ Wk,
    const float* __restrict__ Wv, const float* __restrict__ Wo,
    const float* __restrict__ W1, const float* __restrict__ W2,
    unsigned short* __restrict__ wtall)
{
    int b = blockIdx.x;
    const int l = b / 3072;
    b -= l * 3072;
    const size_t sq = (size_t)l * 1048576;          // 1M elems per square weight
    const size_t sr = (size_t)l * 4194304;          // 4M elems per rect weight
    unsigned short* wt = wtall + (size_t)l * (12 * 1048576);
    const float* W; unsigned short* out; int K, N, t;
    if (b < 768)       { int w = b >> 8; t = b & 255;
                         W = (w == 0 ? Wq : (w == 1 ? Wk : Wv)) + sq;
                         out = wt + (size_t)w * 1048576; K = 1024; N = 1024; }
    else if (b < 1024) { t = b - 768;  W = Wo + sq; out = wt + (size_t)3 * 1048576; K = 1024; N = 1024; }
    else if (b < 2048) { t = b - 1024; W = W1 + sr; out = wt + (size_t)4 * 1048576; K = 1024; N = 4096; }
    else               { t = b - 2048; W = W2 + sr; out = wt + (size_t)8 * 1048576; K = 4096; N = 1024; }
    int ntx = N >> 6;
    tc_tile(W, out, K, N, (t % ntx) * 64, (t / ntx) * 64);
}

// ---------------- small NT GEMM (m97 128x128) with split-K support ----------------
// MODE 1: bf16 out; MODE 2: relu->bf16 out.
template<int MODE>
__global__ __launch_bounds__(256, 3) void gemm_bt(
    const unsigned short* __restrict__ A, int lda,
    const unsigned short* __restrict__ Bt, int ldb,
    const float* __restrict__ bias, void* __restrict__ Cout, int N, int Klen)
{
    __shared__ unsigned short As[128 * 32];
    __shared__ unsigned short Bs[128 * 32];
    const int part = blockIdx.y;
    A  += (size_t)part * Klen;
    Bt += (size_t)part * Klen;
    int flat = blockIdx.x;
    const int bm = flat & 31, bn = flat >> 5;
    const int tid  = threadIdx.x;
    const int wid  = tid >> 6, lane = tid & 63;
    const int l16  = lane & 15, lhi = lane >> 4;
    const int wr   = wid >> 1, wc = wid & 1;

    const int srow = wid * 32 + (lane >> 2);
    const int scol = (lane & 3) * 8;
    const unsigned short* gA0 = A  + ((size_t)bm * 128 + srow) * lda + scol;
    const unsigned short* gB0 = Bt + ((size_t)bn * 128 + srow) * ldb + scol;
    unsigned short* lA = As + wid * 32 * 32;
    unsigned short* lB = Bs + wid * 32 * 32;

    f32x4 acc[4][4];
#pragma unroll
    for (int i = 0; i < 4; i++)
#pragma unroll
        for (int j = 0; j < 4; j++) acc[i][j] = (f32x4){0.f, 0.f, 0.f, 0.f};

    for (int k0 = 0; k0 < Klen; k0 += 32) {
        __syncthreads();
        gld16(gA0 + k0,                    lA);
        gld16(gA0 + k0 + 16 * (size_t)lda, lA + 16 * 32);
        gld16(gB0 + k0,                    lB);
        gld16(gB0 + k0 + 16 * (size_t)ldb, lB + 16 * 32);
        __syncthreads();
        u16x8 af[4], bfr[4];
#pragma unroll
        for (int i = 0; i < 4; i++)
            af[i] = *(const u16x8*)(As + (wr * 64 + i * 16 + l16) * 32 + lhi * 8);
#pragma unroll
        for (int i = 0; i < 4; i++)
            bfr[i] = *(const u16x8*)(Bs + (wc * 64 + i * 16 + l16) * 32 + lhi * 8);
#pragma unroll
        for (int mi = 0; mi < 4; mi++)
#pragma unroll
            for (int ni = 0; ni < 4; ni++)
                acc[mi][ni] = mfma32(af[mi], bfr[ni], acc[mi][ni]);
    }

    const size_t pofs = (size_t)part * (size_t)ROWS * N;
    // epilogue: j-then-ni order so 4 stores cover 128B contiguous per row
#pragma unroll
    for (int mi = 0; mi < 4; mi++) {
        float bv[4];
#pragma unroll
        for (int ni = 0; ni < 4; ni++)
            bv[ni] = (bias && part == 0) ? bias[bn * 128 + wc * 64 + ni * 16 + l16] : 0.f;
#pragma unroll
        for (int j = 0; j < 4; j++) {
            int row = bm * 128 + wr * 64 + mi * 16 + lhi * 4 + j;
#pragma unroll
            for (int ni = 0; ni < 4; ni++) {
                int col = bn * 128 + wc * 64 + ni * 16 + l16;
                float v = acc[mi][ni][j] + bv[ni];
                size_t idx = pofs + (size_t)row * N + col;
                if constexpr (MODE == 1) {
                    ((unsigned short*)Cout)[idx] = f2bf(v);
                } else {
                    ((unsigned short*)Cout)[idx] = f2bf(v > 0.f ? v : 0.f);
                }
            }
        }
    }
}

// ================= 256x256 8-phase GEMM (R4-best structure + NT store) =================
#define PSYNC() do { __builtin_amdgcn_s_barrier(); \
    asm volatile("s_waitcnt lgkmcnt(0)" ::: "memory"); \
    __builtin_amdgcn_sched_barrier(0); } while (0)
#define PEND() __builtin_amdgcn_s_barrier()
#define VM4()  asm volatile("s_waitcnt vmcnt(4)" ::: "memory")

#define LOADA(reg, half) do { \
    _Pragma("unroll") \
    for (int m_ = 0; m_ < 4; m_++) { \
        aF[m_][0] = *(const u16x8*)((reg) + ((half)*4 + m_) * 2048 + lane0); \
        aF[m_][1] = *(const u16x8*)((reg) + ((half)*4 + m_) * 2048 + lane1); \
    } } while (0)

#define LOADB(reg, np) do { \
    _Pragma("unroll") \
    for (int n_ = 0; n_ < 2; n_++) { \
        bF[(np)*2 + n_][0] = *(const u16x8*)((reg) + ((np)*2 + n_) * 2048 + lane0); \
        bF[(np)*2 + n_][1] = *(const u16x8*)((reg) + ((np)*2 + n_) * 2048 + lane1); \
    } } while (0)

#define MFMA8(ma, np) do { \
    __builtin_amdgcn_s_setprio(1); \
    _Pragma("unroll") \
    for (int m_ = 0; m_ < 4; m_++) \
        _Pragma("unroll") \
        for (int n_ = 0; n_ < 2; n_++) { \
            acc[(ma)+m_][(np)*2+n_] = mfma32(aF[m_][0], bF[(np)*2+n_][0], acc[(ma)+m_][(np)*2+n_]); \
            acc[(ma)+m_][(np)*2+n_] = mfma32(aF[m_][1], bF[(np)*2+n_][1], acc[(ma)+m_][(np)*2+n_]); \
        } \
    __builtin_amdgcn_s_setprio(0); \
} while (0)

template<int MODE, int SWZ>
__global__ __launch_bounds__(512, 2) void gemm256(
    const unsigned short* __restrict__ A, const unsigned short* __restrict__ Bt,
    const float* __restrict__ bias, void* __restrict__ Cout, int N, int K)
{
    __shared__ unsigned short lds[65536] __attribute__((aligned(128)));
    const int tid = threadIdx.x, wid = tid >> 6, lane = tid & 63;
    const int l16 = lane & 15, lhi = lane >> 4;
    const int wr = wid >> 2, wc = wid & 3;

    int flat = blockIdx.x;
    if constexpr (SWZ) {
        int cpx = gridDim.x >> 3; flat = (flat & 7) * cpx + (flat >> 3);
    }
    const int bm = flat & 15, bn = flat >> 4;
    const int NT = K >> 6;

    const int srowL = tid >> 3;                                      // 0..63
    const int scolb = ((tid & 7) << 4) ^ (((tid >> 3) & 7) << 4);    // bytes (pre-swz src)
    const unsigned short* baseA = A  + (size_t)(bm * 256 + srowL) * K + (scolb >> 1);
    const unsigned short* baseB = Bt + (size_t)(bn * 256 + srowL) * K + (scolb >> 1);
    unsigned short* dst0 = lds + wid * 512;   // wave-uniform; HW adds lane*16B

    auto stage = [&](int isB, int tile, int h) {   // one half-tile = 2 gld16
        const unsigned short* s = (isB ? baseB : baseA) + (size_t)(h * 128) * K + (size_t)tile * 64;
        unsigned short* d = dst0 + (tile & 1) * 32768 + isB * 16384 + h * 8192;
        gld16(s, d);
        gld16(s + (size_t)64 * K, d + 4096);
    };

    const int lswz  = (l16 & 7) << 4;
    const int lane0 = ((lhi * 16) ^ lswz) + l16 * 128;
    const int lane1 = ((64 + lhi * 16) ^ lswz) + l16 * 128;

    const char* aR0 = (const char*)lds + wr * 16384;
    const char* bR0 = (const char*)lds + 32768 + (wc >> 1) * 16384 + (wc & 1) * 8192;
    const char* aR1 = aR0 + 65536;
    const char* bR1 = bR0 + 65536;

    f32x4 acc[8][4];
#pragma unroll
    for (int i = 0; i < 8; i++)
#pragma unroll
        for (int j = 0; j < 4; j++) acc[i][j] = (f32x4){0.f, 0.f, 0.f, 0.f};
    u16x8 aF[4][2], bF[4][2];

    // prologue: B(0),A(0),B(1); leave B(1)'s 4 loads in flight
    stage(1, 0, 0); stage(1, 0, 1);
    stage(0, 0, 0); stage(0, 0, 1);
    stage(1, 1, 0); stage(1, 1, 1);
    VM4();
    __builtin_amdgcn_s_barrier();

    for (int t = 0; t < NT; t += 2) {
        const bool more = (t + 2) < NT;
        // ---- K-tile t (buf0) ----
        LOADA(aR0, 0); LOADB(bR0, 0); stage(0, t + 1, 0);
        PSYNC(); MFMA8(0, 0); PEND();
        LOADB(bR0, 1);                stage(0, t + 1, 1);
        PSYNC(); MFMA8(0, 1); PEND();
        LOADA(aR0, 1);                if (more) stage(1, t + 2, 0);
        PSYNC(); MFMA8(4, 0); PEND();
        if (more) { stage(1, t + 2, 1); VM4(); }
        else      { asm volatile("s_waitcnt vmcnt(0)" ::: "memory"); }
        PSYNC(); MFMA8(4, 1); PEND();
        // ---- K-tile t+1 (buf1) ----
        LOADA(aR1, 0); LOADB(bR1, 0); if (more) stage(0, t + 2, 0);
        PSYNC(); MFMA8(0, 0); PEND();
        LOADB(bR1, 1);                if (more) stage(0, t + 2, 1);
        PSYNC(); MFMA8(0, 1); PEND();
        LOADA(aR1, 1);                if (more) stage(1, t + 3, 0);
        PSYNC(); MFMA8(4, 0); PEND();
        if (more) { stage(1, t + 3, 1); VM4(); }
        PSYNC(); MFMA8(4, 1); PEND();
    }

    // epilogue: j-then-ni order -> 4 consecutive stores cover one full line
#pragma unroll
    for (int mi = 0; mi < 8; mi++) {
        float bv[4];
#pragma unroll
        for (int ni = 0; ni < 4; ni++)
            bv[ni] = bias ? bias[bn * 256 + wc * 64 + ni * 16 + l16] : 0.f;
#pragma unroll
        for (int j = 0; j < 4; j++) {
            int row = bm * 256 + wr * 128 + mi * 16 + lhi * 4 + j;
#pragma unroll
            for (int ni = 0; ni < 4; ni++) {
                int col = bn * 256 + wc * 64 + ni * 16 + l16;
                float v = acc[mi][ni][j] + bv[ni];
                size_t idx = (size_t)row * N + col;
                if constexpr (MODE == 0) {
                    __builtin_nontemporal_store(v, (float*)Cout + idx);
                } else if constexpr (MODE == 1) {
                    ((unsigned short*)Cout)[idx] = f2bf(v);
                } else {
                    ((unsigned short*)Cout)[idx] = f2bf(v > 0.f ? v : 0.f);
                }
            }
        }
    }
}

// ---------------- flash attention (causal), PAIRED q-tiles for triangle balance ----
__global__ __launch_bounds__(256, 3) void attn_fwd(
    const unsigned short* __restrict__ qkv, unsigned short* __restrict__ ctxb)
{
    __shared__ unsigned short Ks[64 * 72];
    __shared__ unsigned short Vs[64 * 72];   // transposed: Vs[d][kv]
    __shared__ unsigned short Ps[4 * 16 * 72];
    const int tid = threadIdx.x;
    const int wid = tid >> 6, lane = tid & 63;
    const int l16 = lane & 15, lhi = lane >> 4;
    const int bh  = blockIdx.y, b = bh >> 4, h = bh & 15;
    const int p   = blockIdx.x;          // 0..7
    const int qA0 = p * 64;
    const int qB0 = (15 - p) * 64;
    const size_t rowbase = (size_t)b * SEQ;

    const unsigned short* qpA = qkv + (rowbase + qA0 + wid * 16 + l16) * QKV_N + h * HDIM + lhi * 8;
    u16x8 qAf0 = *(const u16x8*)qpA;
    u16x8 qAf1 = *(const u16x8*)(qpA + 32);
    const unsigned short* qpB = qkv + (rowbase + qB0 + wid * 16 + l16) * QKV_N + h * HDIM + lhi * 8;
    u16x8 qBf0 = *(const u16x8*)qpB;
    u16x8 qBf1 = *(const u16x8*)(qpB + 32);

    f32x4 oaA[4], oaB[4];
    float mjA[4], ljA[4], mjB[4], ljB[4];
#pragma unroll
    for (int i = 0; i < 4; i++) {
        oaA[i] = (f32x4){0.f, 0.f, 0.f, 0.f};
        oaB[i] = (f32x4){0.f, 0.f, 0.f, 0.f};
        mjA[i] = -1e30f; ljA[i] = 0.f;
        mjB[i] = -1e30f; ljB[i] = 0.f;
    }

    auto update = [&](u16x8 qf0, u16x8 qf1, f32x4 (&oa)[4],
                      float (&mj)[4], float (&lj)[4], int q0, int kv0) {
        f32x4 sa[4];
        __builtin_amdgcn_s_setprio(1);
#pragma unroll
        for (int ni = 0; ni < 4; ni++) {
            f32x4 z = (f32x4){0.f, 0.f, 0.f, 0.f};
            u16x8 k0f = *(const u16x8*)(&Ks[(ni * 16 + l16) * 72 + lhi * 8]);
            u16x8 k1f = *(const u16x8*)(&Ks[(ni * 16 + l16) * 72 + 32 + lhi * 8]);
            z = mfma32(qf0, k0f, z);
            z = mfma32(qf1, k1f, z);
            sa[ni] = z;
        }
        __builtin_amdgcn_s_setprio(0);
        float tm[4] = {-1e30f, -1e30f, -1e30f, -1e30f};
#pragma unroll
        for (int ni = 0; ni < 4; ni++)
#pragma unroll
            for (int j = 0; j < 4; j++) {
                float v = sa[ni][j] * 0.125f;
                int row = q0 + wid * 16 + lhi * 4 + j;
                int col = kv0 + ni * 16 + l16;
                if (col > row) v = -1e30f;
                sa[ni][j] = v;
                tm[j] = fmaxf(tm[j], v);
            }
#pragma unroll
        for (int j = 0; j < 4; j++) {
#pragma unroll
            for (int off = 1; off < 16; off <<= 1)
                tm[j] = fmaxf(tm[j], __shfl_xor(tm[j], off));
        }
        float al[4], rs[4] = {0.f, 0.f, 0.f, 0.f};
#pragma unroll
        for (int j = 0; j < 4; j++) {
            float mn = fmaxf(mj[j], tm[j]);
            al[j] = __expf(mj[j] - mn);
            mj[j] = mn;
        }
#pragma unroll
        for (int ni = 0; ni < 4; ni++)
#pragma unroll
            for (int j = 0; j < 4; j++) {
                float pv = __expf(sa[ni][j] - mj[j]);
                rs[j] += pv;
                Ps[wid * 1152 + (lhi * 4 + j) * 72 + ni * 16 + l16] = f2bf(pv);
            }
#pragma unroll
        for (int j = 0; j < 4; j++) {
#pragma unroll
            for (int off = 1; off < 16; off <<= 1)
                rs[j] += __shfl_xor(rs[j], off);
            lj[j] = lj[j] * al[j] + rs[j];
        }
#pragma unroll
        for (int di = 0; di < 4; di++)
#pragma unroll
            for (int j = 0; j < 4; j++) oa[di][j] *= al[j];
        __builtin_amdgcn_s_setprio(1);
#pragma unroll
        for (int di = 0; di < 4; di++) {
#pragma unroll
            for (int kc = 0; kc < 2; kc++) {
                u16x8 pf = *(const u16x8*)(&Ps[wid * 1152 + l16 * 72 + kc * 32 + lhi * 8]);
                u16x8 vf = *(const u16x8*)(&Vs[(di * 16 + l16) * 72 + kc * 32 + lhi * 8]);
                oa[di] = mfma32(pf, vf, oa[di]);
            }
        }
        __builtin_amdgcn_s_setprio(0);
    };

    const int ntB = 16 - p;   // kv tiles 0..15-p (covers both q-tiles)
    for (int kt = 0; kt < ntB; ++kt) {
        const int kv0 = kt * 64;
        __syncthreads();
        // K staging: vector writes, row-major
#pragma unroll
        for (int it = 0; it < 2; ++it) {
            int e = it * 256 + tid;
            int r = e >> 3, d0 = (e & 7) * 8;
            size_t goff = (rowbase + kv0 + r) * QKV_N + D_MODEL + h * HDIM + d0;
            u16x8 kk = *(const u16x8*)(qkv + goff);
            *(u16x8*)(&Ks[r * 72 + d0]) = kk;
        }
        // V staging: 128 threads x 4 rows -> transposed via register repack
        if (tid < 128) {
            int r0 = (tid & 15) * 4, d0v = (tid >> 4) * 8;
            const unsigned short* vp = qkv + (rowbase + kv0 + r0) * QKV_N
                                       + 2 * D_MODEL + h * HDIM + d0v;
            u16x8 w0 = *(const u16x8*)vp;
            u16x8 w1 = *(const u16x8*)(vp + QKV_N);
            u16x8 w2 = *(const u16x8*)(vp + 2 * QKV_N);
            u16x8 w3 = *(const u16x8*)(vp + 3 * QKV_N);
#pragma unroll
            for (int j = 0; j < 8; j++) {
                unsigned long long pk = (unsigned long long)w0[j]
                    | ((unsigned long long)w1[j] << 16)
                    | ((unsigned long long)w2[j] << 32)
                    | ((unsigned long long)w3[j] << 48);
                *(unsigned long long*)(&Vs[(d0v + j) * 72 + r0]) = pk;
            }
        }
        __syncthreads();

        if (kt <= p) update(qAf0, qAf1, oaA, mjA, ljA, qA0, kv0);  // block-uniform
        update(qBf0, qBf1, oaB, mjB, ljB, qB0, kv0);
    }

#pragma unroll
    for (int di = 0; di < 4; di++)
#pragma unroll
        for (int j = 0; j < 4; j++) {
            int rowA = qA0 + wid * 16 + lhi * 4 + j;
            ctxb[(rowbase + rowA) * D_MODEL + h * HDIM + di * 16 + l16] =
                f2bf(oaA[di][j] / ljA[j]);
            int rowB = qB0 + wid * 16 + lhi * 4 + j;
            ctxb[(rowbase + rowB) * D_MODEL + h * HDIM + di * 16 + l16] =
                f2bf(oaB[di][j] / ljB[j]);
        }
}

// ------- fused residual(xb + p0 + p1) + LayerNorm, bf16 in-place residual -------
__global__ __launch_bounds__(256) void ln3(
    unsigned short* __restrict__ xb, const unsigned short* __restrict__ p0,
    const unsigned short* __restrict__ p1,
    const float* __restrict__ sc, const float* __restrict__ bi)
{
    const int row = blockIdx.x;
    const int t = threadIdx.x;
    const size_t base = (size_t)row * D_MODEL + t * 4;
    ushort4 xu = *(const ushort4*)(xb + base);
    ushort4 au = *(const ushort4*)(p0 + base);
    ushort4 bu = *(const ushort4*)(p1 + base);
    float v0 = bf2f(xu.x) + bf2f(au.x) + bf2f(bu.x);
    float v1 = bf2f(xu.y) + bf2f(au.y) + bf2f(bu.y);
    float v2 = bf2f(xu.z) + bf2f(au.z) + bf2f(bu.z);
    float v3 = bf2f(xu.w) + bf2f(au.w) + bf2f(bu.w);
    float sum = v0 + v1 + v2 + v3;
    float sq  = v0 * v0 + v1 * v1 + v2 * v2 + v3 * v3;
#pragma unroll
    for (int off = 1; off < 64; off <<= 1) {
        sum += __shfl_xor(sum, off);
        sq  += __shfl_xor(sq, off);
    }
    __shared__ float red[8];
    int wid = t >> 6, lane = t & 63;
    if (lane == 0) { red[wid] = sum; red[4 + wid] = sq; }
    __syncthreads();
    sum = red[0] + red[1] + red[2] + red[3];
    sq  = red[4] + red[5] + red[6] + red[7];
    float mu   = sum * (1.f / D_MODEL);
    float var  = sq * (1.f / D_MODEL) - mu * mu;
    float rstd = rsqrtf(var + LN_EPS);
    int c = t * 4;
    float4 sv = *(const float4*)(sc + c);
    float4 bv = *(const float4*)(bi + c);
    float y0 = sv.x * (v0 - mu) * rstd + bv.x;
    float y1 = sv.y * (v1 - mu) * rstd + bv.y;
    float y2 = sv.z * (v2 - mu) * rstd + bv.z;
    float y3 = sv.w * (v3 - mu) * rstd + bv.w;
    unsigned long long pk = (unsigned long long)f2bf(y0)
        | ((unsigned long long)f2bf(y1) << 16)
        | ((unsigned long long)f2bf(y2) << 32)
        | ((unsigned long long)f2bf(y3) << 48);
    *(unsigned long long*)(xb + base) = pk;
}

// ---------------- launcher ----------------
extern "C" void kernel_launch(void* const* d_in, const int* in_sizes, int n_in,
                              void* d_out, int out_size, void* d_ws, size_t ws_size,
                              hipStream_t stream)
{
    (void)in_sizes; (void)n_in; (void)out_size;
    const int*   tokens = (const int*)d_in[0];
    const float* emb  = (const float*)d_in[2];
    const float* pose = (const float*)d_in[3];
    const float* Wq = (const float*)d_in[4];
    const float* bq = (const float*)d_in[5];
    const float* Wk = (const float*)d_in[6];
    const float* bk = (const float*)d_in[7];
    const float* Wv = (const float*)d_in[8];
    const float* bv = (const float*)d_in[9];
    const float* Wo = (const float*)d_in[10];
    const float* bo = (const float*)d_in[11];
    const float* n1s = (const float*)d_in[12];
    const float* n1b = (const float*)d_in[13];
    const float* W1 = (const float*)d_in[14];
    const float* b1 = (const float*)d_in[15];
    const float* W2 = (const float*)d_in[16];
    const float* b2 = (const float*)d_in[17];
    const float* n2s = (const float*)d_in[18];
    const float* n2b = (const float*)d_in[19];

    char* w = (char*)d_ws;
    size_t off = 0;
    auto carve = [&](size_t bytes) -> void* {
        void* p = w + off;
        off = (off + bytes + 255) & ~(size_t)255;
        return p;
    };
    unsigned short* tmp = (unsigned short*)carve((size_t)2 * ROWS * D_MODEL * 2);  // bf16 partials
    unsigned short* xb    = (unsigned short*)carve((size_t)ROWS * D_MODEL * 2);   // bf16 residual
    unsigned short* qkvb  = (unsigned short*)carve((size_t)ROWS * QKV_N * 2);
    unsigned short* cbuf  = (unsigned short*)carve((size_t)ROWS * D_MODEL * 2);
    unsigned short* hbuf  = (unsigned short*)carve((size_t)ROWS * FF_DIM * 2);
    float* bqkv = (float*)carve((size_t)NLAYER * QKV_N * 4);
    unsigned short* embb = qkvb;   // tied-head emb aliases dead qkv/ctx/h region
    unsigned short* tmp1 = tmp + (size_t)ROWS * D_MODEL;

    // preferred: ALL layers' weights transposed upfront (201 MB)
    size_t big_off = off;
    unsigned short* wtall = (unsigned short*)carve((size_t)NLAYER * 12 * 1048576 * 2);
    bool all_t = (off <= ws_size);
    unsigned short* wt = nullptr;
    if (!all_t) {
        off = big_off;
        wt = (unsigned short*)carve((size_t)12 * 1048576 * 2);  // per-layer fused (24MB)
        if (off > ws_size) return;
    }

    bias3_k<<<NLAYER * 3, 256, 0, stream>>>(bq, bk, bv, bqkv);
    embed_k<<<ROWS, 256, 0, stream>>>(tokens, emb, pose, xb);
    if (all_t)
        transpose_all_L<<<NLAYER * 3072, 256, 0, stream>>>(Wq, Wk, Wv, Wo, W1, W2, wtall);

    for (int l = 0; l < NLAYER; l++) {
        unsigned short* wl = all_t ? wtall + (size_t)l * (12 * 1048576) : wt;
        unsigned short* wtQKV = wl;
        unsigned short* wtWo  = wl + (size_t)3 * 1048576;
        unsigned short* wtW1  = wl + (size_t)4 * 1048576;
        unsigned short* wtW2  = wl + (size_t)8 * 1048576;

        if (!all_t) {
            transpose_all<<<3072, 256, 0, stream>>>(
                Wq + (size_t)l * D_MODEL * D_MODEL, Wk + (size_t)l * D_MODEL * D_MODEL,
                Wv + (size_t)l * D_MODEL * D_MODEL, Wo + (size_t)l * D_MODEL * D_MODEL,
                W1 + (size_t)l * D_MODEL * FF_DIM,  W2 + (size_t)l * FF_DIM * D_MODEL, wt);
        }
        // QKV: gemm256, 192 blocks (one round, same per-block tile as FFN1)
        gemm256<1, 1><<<(QKV_N / 256) * 16, 512, 0, stream>>>(xb, wtQKV,
            bqkv + (size_t)l * QKV_N, qkvb, QKV_N, D_MODEL);

        attn_fwd<<<dim3(8, BATCH * NHEAD), 256, 0, stream>>>(qkvb, cbuf);

        gemm_bt<1><<<dim3(256, 2), 256, 0, stream>>>(cbuf, D_MODEL, wtWo, D_MODEL,
                                                     bo + (size_t)l * D_MODEL, tmp, D_MODEL, D_MODEL / 2);
        ln3<<<ROWS, 256, 0, stream>>>(xb, tmp, tmp1, n1s + (size_t)l * D_MODEL, n1b + (size_t)l * D_MODEL);

        gemm256<2, 1><<<(FF_DIM / 256) * 16, 512, 0, stream>>>(xb, wtW1, b1 + (size_t)l * FF_DIM, hbuf, FF_DIM, D_MODEL);
        gemm_bt<1><<<dim3(256, 2), 256, 0, stream>>>(hbuf, FF_DIM, wtW2, FF_DIM,
                                                     b2 + (size_t)l * D_MODEL, tmp, D_MODEL, FF_DIM / 2);
        ln3<<<ROWS, 256, 0, stream>>>(xb, tmp, tmp1, n2s + (size_t)l * D_MODEL, n2b + (size_t)l * D_MODEL);
    }

    cast_bf<<<(VOCAB * D_MODEL) / 1024, 256, 0, stream>>>(emb, embb, (size_t)VOCAB * D_MODEL);
    // head: NO XCD swizzle — bm-fastest order shares B panels via L3
    gemm256<0, 0><<<(VOCAB / 256) * 16, 512, 0, stream>>>(xb, embb, nullptr, d_out, VOCAB, D_MODEL);
}

// Round 14
// 1969.179 us; speedup vs baseline: 1.0806x; 1.0806x over previous
//
#include <hip/hip_runtime.h>

#define D_MODEL 1024
#define SEQ     1024
#define BATCH   4
#define NHEAD   16
#define HDIM    64
#define FF_DIM  4096
#define NLAYER  8
#define VOCAB   32000
#define ROWS    (BATCH*SEQ)
#define QKV_N   3072
#define LN_EPS  1e-5f

typedef __attribute__((ext_vector_type(4))) float   f32x4;
typedef __attribute__((ext_vector_type(8))) unsigned short u16x8;
typedef __attribute__((ext_vector_type(8))) __bf16  bf16x8;

typedef const unsigned int __attribute__((address_space(1)))* gas_t;
typedef unsigned int __attribute__((address_space(3)))* las_t;

__device__ __forceinline__ void gld16(const void* g, void* l) {
    __builtin_amdgcn_global_load_lds((gas_t)g, (las_t)l, 16, 0, 0);
}

__device__ __forceinline__ unsigned short f2bf(float f) {
    unsigned int u = __builtin_bit_cast(unsigned int, f);
    u += 0x7FFFu + ((u >> 16) & 1u);   // RNE
    return (unsigned short)(u >> 16);
}

__device__ __forceinline__ float bf2f(unsigned short u) {
    return __builtin_bit_cast(float, (unsigned int)u << 16);
}

__device__ __forceinline__ f32x4 mfma32(u16x8 a, u16x8 b, f32x4 c) {
    return __builtin_amdgcn_mfma_f32_16x16x32_bf16(
        __builtin_bit_cast(bf16x8, a), __builtin_bit_cast(bf16x8, b), c, 0, 0, 0);
}

// ---------------- embed: xb = bf16(emb[tok] + pos) ----------------
__global__ __launch_bounds__(256) void embed_k(
    const int* __restrict__ tok, const float* __restrict__ emb,
    const float* __restrict__ pos, unsigned short* __restrict__ xb)
{
    int bs = blockIdx.x;
    int s  = bs & (SEQ - 1);
    int tk = tok[bs];
    int c  = threadIdx.x * 4;
    float4 e = *(const float4*)(emb + (size_t)tk * D_MODEL + c);
    float4 p = *(const float4*)(pos + (size_t)s * D_MODEL + c);
    float y0 = e.x + p.x, y1 = e.y + p.y, y2 = e.z + p.z, y3 = e.w + p.w;
    size_t base = (size_t)bs * D_MODEL + c;
    unsigned long long pk = (unsigned long long)f2bf(y0)
        | ((unsigned long long)f2bf(y1) << 16)
        | ((unsigned long long)f2bf(y2) << 32)
        | ((unsigned long long)f2bf(y3) << 48);
    *(unsigned long long*)(xb + base) = pk;
}

// ---------------- cast fp32 -> bf16 ----------------
__global__ __launch_bounds__(256) void cast_bf(
    const float* __restrict__ in, unsigned short* __restrict__ out, size_t n)
{
    size_t i = ((size_t)blockIdx.x * 256 + threadIdx.x) * 4;
    if (i >= n) return;
    float4 v = *(const float4*)(in + i);
    unsigned long long pk = (unsigned long long)f2bf(v.x)
        | ((unsigned long long)f2bf(v.y) << 16)
        | ((unsigned long long)f2bf(v.z) << 32)
        | ((unsigned long long)f2bf(v.w) << 48);
    *(unsigned long long*)(out + i) = pk;
}

// ---------------- concat qkv biases ----------------
__global__ __launch_bounds__(256) void bias3_k(
    const float* __restrict__ bq, const float* __restrict__ bk,
    const float* __restrict__ bv, float* __restrict__ out)
{
    int l = blockIdx.x / 3, which = blockIdx.x % 3;
    const float* src = which == 0 ? bq : (which == 1 ? bk : bv);
    int i = threadIdx.x * 4;
    float4 v = *(const float4*)(src + (size_t)l * D_MODEL + i);
    *(float4*)(out + (size_t)l * QKV_N + which * D_MODEL + i) = v;
}

// ---------------- transpose tile body (shared) ----------------
__device__ __forceinline__ void tc_tile(
    const float* __restrict__ W, unsigned short* __restrict__ Wt,
    int K, int N, int n0, int k0)
{
    __shared__ float t[64][65];
    int rr = threadIdx.x >> 4;          // 0..15
    int cc = (threadIdx.x & 15) * 4;    // 0..60
#pragma unroll
    for (int it = 0; it < 4; it++) {
        int r = it * 16 + rr;
        float4 v = *(const float4*)(W + (size_t)(k0 + r) * N + n0 + cc);
        t[r][cc] = v.x; t[r][cc + 1] = v.y; t[r][cc + 2] = v.z; t[r][cc + 3] = v.w;
    }
    __syncthreads();
#pragma unroll
    for (int it = 0; it < 4; it++) {
        int n = it * 16 + rr;
        unsigned long long pk = (unsigned long long)f2bf(t[cc][n])
            | ((unsigned long long)f2bf(t[cc + 1][n]) << 16)
            | ((unsigned long long)f2bf(t[cc + 2][n]) << 32)
            | ((unsigned long long)f2bf(t[cc + 3][n]) << 48);
        *(unsigned long long*)(Wt + (size_t)(n0 + n) * K + k0 + cc) = pk;
    }
}

// ---------------- per-layer fused transpose: Wq,Wk,Wv,Wo,W1,W2 in ONE launch ----
// wt layout (elems): [0,3M) qkv^T, [3M,4M) Wo^T, [4M,8M) W1^T, [8M,12M) W2^T
__global__ __launch_bounds__(256) void transpose_all(
    const float* __restrict__ Wq, const float* __restrict__ Wk,
    const float* __restrict__ Wv, const float* __restrict__ Wo,
    const float* __restrict__ W1, const float* __restrict__ W2,
    unsigned short* __restrict__ wt)
{
    int b = blockIdx.x;
    const float* W; unsigned short* out; int K, N, t;
    if (b < 768)       { int w = b >> 8; t = b & 255; W = w == 0 ? Wq : (w == 1 ? Wk : Wv);
                         out = wt + (size_t)w * 1048576; K = 1024; N = 1024; }
    else if (b < 1024) { t = b - 768;  W = Wo; out = wt + (size_t)3 * 1048576; K = 1024; N = 1024; }
    else if (b < 2048) { t = b - 1024; W = W1; out = wt + (size_t)4 * 1048576; K = 1024; N = 4096; }
    else               { t = b - 2048; W = W2; out = wt + (size_t)8 * 1048576; K = 4096; N = 1024; }
    int ntx = N >> 6;
    tc_tile(W, out, K, N, (t % ntx) * 64, (t / ntx) * 64);
}

// ---------------- small NT GEMM (m97 128x128) with split-K support ----------------
// MODE 1: bf16 out; MODE 2: relu->bf16 out.
template<int MODE>
__global__ __launch_bounds__(256, 3) void gemm_bt(
    const unsigned short* __restrict__ A, int lda,
    const unsigned short* __restrict__ Bt, int ldb,
    const float* __restrict__ bias, void* __restrict__ Cout, int N, int Klen)
{
    __shared__ unsigned short As[128 * 32];
    __shared__ unsigned short Bs[128 * 32];
    const int part = blockIdx.y;
    A  += (size_t)part * Klen;
    Bt += (size_t)part * Klen;
    int flat = blockIdx.x;
    const int bm = flat & 31, bn = flat >> 5;
    const int tid  = threadIdx.x;
    const int wid  = tid >> 6, lane = tid & 63;
    const int l16  = lane & 15, lhi = lane >> 4;
    const int wr   = wid >> 1, wc = wid & 1;

    const int srow = wid * 32 + (lane >> 2);
    const int scol = (lane & 3) * 8;
    const unsigned short* gA0 = A  + ((size_t)bm * 128 + srow) * lda + scol;
    const unsigned short* gB0 = Bt + ((size_t)bn * 128 + srow) * ldb + scol;
    unsigned short* lA = As + wid * 32 * 32;
    unsigned short* lB = Bs + wid * 32 * 32;

    f32x4 acc[4][4];
#pragma unroll
    for (int i = 0; i < 4; i++)
#pragma unroll
        for (int j = 0; j < 4; j++) acc[i][j] = (f32x4){0.f, 0.f, 0.f, 0.f};

    for (int k0 = 0; k0 < Klen; k0 += 32) {
        __syncthreads();
        gld16(gA0 + k0,                    lA);
        gld16(gA0 + k0 + 16 * (size_t)lda, lA + 16 * 32);
        gld16(gB0 + k0,                    lB);
        gld16(gB0 + k0 + 16 * (size_t)ldb, lB + 16 * 32);
        __syncthreads();
        u16x8 af[4], bfr[4];
#pragma unroll
        for (int i = 0; i < 4; i++)
            af[i] = *(const u16x8*)(As + (wr * 64 + i * 16 + l16) * 32 + lhi * 8);
#pragma unroll
        for (int i = 0; i < 4; i++)
            bfr[i] = *(const u16x8*)(Bs + (wc * 64 + i * 16 + l16) * 32 + lhi * 8);
#pragma unroll
        for (int mi = 0; mi < 4; mi++)
#pragma unroll
            for (int ni = 0; ni < 4; ni++)
                acc[mi][ni] = mfma32(af[mi], bfr[ni], acc[mi][ni]);
    }

    const size_t pofs = (size_t)part * (size_t)ROWS * N;
    // epilogue: j-then-ni order so 4 stores cover 128B contiguous per row
#pragma unroll
    for (int mi = 0; mi < 4; mi++) {
        float bv[4];
#pragma unroll
        for (int ni = 0; ni < 4; ni++)
            bv[ni] = (bias && part == 0) ? bias[bn * 128 + wc * 64 + ni * 16 + l16] : 0.f;
#pragma unroll
        for (int j = 0; j < 4; j++) {
            int row = bm * 128 + wr * 64 + mi * 16 + lhi * 4 + j;
#pragma unroll
            for (int ni = 0; ni < 4; ni++) {
                int col = bn * 128 + wc * 64 + ni * 16 + l16;
                float v = acc[mi][ni][j] + bv[ni];
                size_t idx = pofs + (size_t)row * N + col;
                if constexpr (MODE == 1) {
                    ((unsigned short*)Cout)[idx] = f2bf(v);
                } else {
                    ((unsigned short*)Cout)[idx] = f2bf(v > 0.f ? v : 0.f);
                }
            }
        }
    }
}

// ====== 256x256 8-phase GEMM (R4-best structure + NT store), split-K capable ======
#define PSYNC() do { __builtin_amdgcn_s_barrier(); \
    asm volatile("s_waitcnt lgkmcnt(0)" ::: "memory"); \
    __builtin_amdgcn_sched_barrier(0); } while (0)
#define PEND() __builtin_amdgcn_s_barrier()
#define VM4()  asm volatile("s_waitcnt vmcnt(4)" ::: "memory")

#define LOADA(reg, half) do { \
    _Pragma("unroll") \
    for (int m_ = 0; m_ < 4; m_++) { \
        aF[m_][0] = *(const u16x8*)((reg) + ((half)*4 + m_) * 2048 + lane0); \
        aF[m_][1] = *(const u16x8*)((reg) + ((half)*4 + m_) * 2048 + lane1); \
    } } while (0)

#define LOADB(reg, np) do { \
    _Pragma("unroll") \
    for (int n_ = 0; n_ < 2; n_++) { \
        bF[(np)*2 + n_][0] = *(const u16x8*)((reg) + ((np)*2 + n_) * 2048 + lane0); \
        bF[(np)*2 + n_][1] = *(const u16x8*)((reg) + ((np)*2 + n_) * 2048 + lane1); \
    } } while (0)

#define MFMA8(ma, np) do { \
    __builtin_amdgcn_s_setprio(1); \
    _Pragma("unroll") \
    for (int m_ = 0; m_ < 4; m_++) \
        _Pragma("unroll") \
        for (int n_ = 0; n_ < 2; n_++) { \
            acc[(ma)+m_][(np)*2+n_] = mfma32(aF[m_][0], bF[(np)*2+n_][0], acc[(ma)+m_][(np)*2+n_]); \
            acc[(ma)+m_][(np)*2+n_] = mfma32(aF[m_][1], bF[(np)*2+n_][1], acc[(ma)+m_][(np)*2+n_]); \
        } \
    __builtin_amdgcn_s_setprio(0); \
} while (0)

template<int MODE, int SWZ>
__global__ __launch_bounds__(512, 2) void gemm256(
    const unsigned short* __restrict__ A, int lda,
    const unsigned short* __restrict__ Bt, int ldb,
    const float* __restrict__ bias, void* __restrict__ Cout, int N, int Klen)
{
    __shared__ unsigned short lds[65536] __attribute__((aligned(128)));
    const int tid = threadIdx.x, wid = tid >> 6, lane = tid & 63;
    const int l16 = lane & 15, lhi = lane >> 4;
    const int wr = wid >> 2, wc = wid & 3;

    const int part = blockIdx.y;
    A  += (size_t)part * Klen;
    Bt += (size_t)part * Klen;

    int flat = blockIdx.x;
    if constexpr (SWZ) {
        int cpx = gridDim.x >> 3; flat = (flat & 7) * cpx + (flat >> 3);
    }
    const int bm = flat & 15, bn = flat >> 4;
    const int NT = Klen >> 6;

    const int srowL = tid >> 3;                                      // 0..63
    const int scolb = ((tid & 7) << 4) ^ (((tid >> 3) & 7) << 4);    // bytes (pre-swz src)
    const unsigned short* baseA = A  + (size_t)(bm * 256 + srowL) * lda + (scolb >> 1);
    const unsigned short* baseB = Bt + (size_t)(bn * 256 + srowL) * ldb + (scolb >> 1);
    unsigned short* dst0 = lds + wid * 512;   // wave-uniform; HW adds lane*16B

    auto stage = [&](int isB, int tile, int h) {   // one half-tile = 2 gld16
        const size_t ld = isB ? (size_t)ldb : (size_t)lda;
        const unsigned short* s = (isB ? baseB : baseA) + (size_t)(h * 128) * ld + (size_t)tile * 64;
        unsigned short* d = dst0 + (tile & 1) * 32768 + isB * 16384 + h * 8192;
        gld16(s, d);
        gld16(s + 64 * ld, d + 4096);
    };

    const int lswz  = (l16 & 7) << 4;
    const int lane0 = ((lhi * 16) ^ lswz) + l16 * 128;
    const int lane1 = ((64 + lhi * 16) ^ lswz) + l16 * 128;

    const char* aR0 = (const char*)lds + wr * 16384;
    const char* bR0 = (const char*)lds + 32768 + (wc >> 1) * 16384 + (wc & 1) * 8192;
    const char* aR1 = aR0 + 65536;
    const char* bR1 = bR0 + 65536;

    f32x4 acc[8][4];
#pragma unroll
    for (int i = 0; i < 8; i++)
#pragma unroll
        for (int j = 0; j < 4; j++) acc[i][j] = (f32x4){0.f, 0.f, 0.f, 0.f};
    u16x8 aF[4][2], bF[4][2];

    // prologue: B(0),A(0),B(1); leave B(1)'s 4 loads in flight
    stage(1, 0, 0); stage(1, 0, 1);
    stage(0, 0, 0); stage(0, 0, 1);
    stage(1, 1, 0); stage(1, 1, 1);
    VM4();
    __builtin_amdgcn_s_barrier();

    for (int t = 0; t < NT; t += 2) {
        const bool more = (t + 2) < NT;
        // ---- K-tile t (buf0) ----
        LOADA(aR0, 0); LOADB(bR0, 0); stage(0, t + 1, 0);
        PSYNC(); MFMA8(0, 0); PEND();
        LOADB(bR0, 1);                stage(0, t + 1, 1);
        PSYNC(); MFMA8(0, 1); PEND();
        LOADA(aR0, 1);                if (more) stage(1, t + 2, 0);
        PSYNC(); MFMA8(4, 0); PEND();
        if (more) { stage(1, t + 2, 1); VM4(); }
        else      { asm volatile("s_waitcnt vmcnt(0)" ::: "memory"); }
        PSYNC(); MFMA8(4, 1); PEND();
        // ---- K-tile t+1 (buf1) ----
        LOADA(aR1, 0); LOADB(bR1, 0); if (more) stage(0, t + 2, 0);
        PSYNC(); MFMA8(0, 0); PEND();
        LOADB(bR1, 1);                if (more) stage(0, t + 2, 1);
        PSYNC(); MFMA8(0, 1); PEND();
        LOADA(aR1, 1);                if (more) stage(1, t + 3, 0);
        PSYNC(); MFMA8(4, 0); PEND();
        if (more) { stage(1, t + 3, 1); VM4(); }
        PSYNC(); MFMA8(4, 1); PEND();
    }

    const size_t pofs = (size_t)part * (size_t)ROWS * N;
    // epilogue: j-then-ni order -> 4 consecutive stores cover one full line
#pragma unroll
    for (int mi = 0; mi < 8; mi++) {
        float bv[4];
#pragma unroll
        for (int ni = 0; ni < 4; ni++)
            bv[ni] = (bias && part == 0) ? bias[bn * 256 + wc * 64 + ni * 16 + l16] : 0.f;
#pragma unroll
        for (int j = 0; j < 4; j++) {
            int row = bm * 256 + wr * 128 + mi * 16 + lhi * 4 + j;
#pragma unroll
            for (int ni = 0; ni < 4; ni++) {
                int col = bn * 256 + wc * 64 + ni * 16 + l16;
                float v = acc[mi][ni][j] + bv[ni];
                size_t idx = pofs + (size_t)row * N + col;
                if constexpr (MODE == 0) {
                    __builtin_nontemporal_store(v, (float*)Cout + idx);
                } else if constexpr (MODE == 1) {
                    ((unsigned short*)Cout)[idx] = f2bf(v);
                } else {
                    ((unsigned short*)Cout)[idx] = f2bf(v > 0.f ? v : 0.f);
                }
            }
        }
    }
}

// ---------------- flash attention (causal), PAIRED q-tiles for triangle balance ----
__global__ __launch_bounds__(256, 3) void attn_fwd(
    const unsigned short* __restrict__ qkv, unsigned short* __restrict__ ctxb)
{
    __shared__ unsigned short Ks[64 * 72];
    __shared__ unsigned short Vs[64 * 72];   // transposed: Vs[d][kv]
    __shared__ unsigned short Ps[4 * 16 * 72];
    const int tid = threadIdx.x;
    const int wid = tid >> 6, lane = tid & 63;
    const int l16 = lane & 15, lhi = lane >> 4;
    const int bh  = blockIdx.y, b = bh >> 4, h = bh & 15;
    const int p   = blockIdx.x;          // 0..7
    const int qA0 = p * 64;
    const int qB0 = (15 - p) * 64;
    const size_t rowbase = (size_t)b * SEQ;

    const unsigned short* qpA = qkv + (rowbase + qA0 + wid * 16 + l16) * QKV_N + h * HDIM + lhi * 8;
    u16x8 qAf0 = *(const u16x8*)qpA;
    u16x8 qAf1 = *(const u16x8*)(qpA + 32);
    const unsigned short* qpB = qkv + (rowbase + qB0 + wid * 16 + l16) * QKV_N + h * HDIM + lhi * 8;
    u16x8 qBf0 = *(const u16x8*)qpB;
    u16x8 qBf1 = *(const u16x8*)(qpB + 32);

    f32x4 oaA[4], oaB[4];
    float mjA[4], ljA[4], mjB[4], ljB[4];
#pragma unroll
    for (int i = 0; i < 4; i++) {
        oaA[i] = (f32x4){0.f, 0.f, 0.f, 0.f};
        oaB[i] = (f32x4){0.f, 0.f, 0.f, 0.f};
        mjA[i] = -1e30f; ljA[i] = 0.f;
        mjB[i] = -1e30f; ljB[i] = 0.f;
    }

    auto update = [&](u16x8 qf0, u16x8 qf1, f32x4 (&oa)[4],
                      float (&mj)[4], float (&lj)[4], int q0, int kv0) {
        f32x4 sa[4];
        __builtin_amdgcn_s_setprio(1);
#pragma unroll
        for (int ni = 0; ni < 4; ni++) {
            f32x4 z = (f32x4){0.f, 0.f, 0.f, 0.f};
            u16x8 k0f = *(const u16x8*)(&Ks[(ni * 16 + l16) * 72 + lhi * 8]);
            u16x8 k1f = *(const u16x8*)(&Ks[(ni * 16 + l16) * 72 + 32 + lhi * 8]);
            z = mfma32(qf0, k0f, z);
            z = mfma32(qf1, k1f, z);
            sa[ni] = z;
        }
        __builtin_amdgcn_s_setprio(0);
        float tm[4] = {-1e30f, -1e30f, -1e30f, -1e30f};
#pragma unroll
        for (int ni = 0; ni < 4; ni++)
#pragma unroll
            for (int j = 0; j < 4; j++) {
                float v = sa[ni][j] * 0.125f;
                int row = q0 + wid * 16 + lhi * 4 + j;
                int col = kv0 + ni * 16 + l16;
                if (col > row) v = -1e30f;
                sa[ni][j] = v;
                tm[j] = fmaxf(tm[j], v);
            }
#pragma unroll
        for (int j = 0; j < 4; j++) {
#pragma unroll
            for (int off = 1; off < 16; off <<= 1)
                tm[j] = fmaxf(tm[j], __shfl_xor(tm[j], off));
        }
        float al[4], rs[4] = {0.f, 0.f, 0.f, 0.f};
#pragma unroll
        for (int j = 0; j < 4; j++) {
            float mn = fmaxf(mj[j], tm[j]);
            al[j] = __expf(mj[j] - mn);
            mj[j] = mn;
        }
#pragma unroll
        for (int ni = 0; ni < 4; ni++)
#pragma unroll
            for (int j = 0; j < 4; j++) {
                float pv = __expf(sa[ni][j] - mj[j]);
                rs[j] += pv;
                Ps[wid * 1152 + (lhi * 4 + j) * 72 + ni * 16 + l16] = f2bf(pv);
            }
#pragma unroll
        for (int j = 0; j < 4; j++) {
#pragma unroll
            for (int off = 1; off < 16; off <<= 1)
                rs[j] += __shfl_xor(rs[j], off);
            lj[j] = lj[j] * al[j] + rs[j];
        }
#pragma unroll
        for (int di = 0; di < 4; di++)
#pragma unroll
            for (int j = 0; j < 4; j++) oa[di][j] *= al[j];
        __builtin_amdgcn_s_setprio(1);
#pragma unroll
        for (int di = 0; di < 4; di++) {
#pragma unroll
            for (int kc = 0; kc < 2; kc++) {
                u16x8 pf = *(const u16x8*)(&Ps[wid * 1152 + l16 * 72 + kc * 32 + lhi * 8]);
                u16x8 vf = *(const u16x8*)(&Vs[(di * 16 + l16) * 72 + kc * 32 + lhi * 8]);
                oa[di] = mfma32(pf, vf, oa[di]);
            }
        }
        __builtin_amdgcn_s_setprio(0);
    };

    const int ntB = 16 - p;   // kv tiles 0..15-p (covers both q-tiles)
    for (int kt = 0; kt < ntB; ++kt) {
        const int kv0 = kt * 64;
        __syncthreads();
        // K staging: vector writes, row-major
#pragma unroll
        for (int it = 0; it < 2; ++it) {
            int e = it * 256 + tid;
            int r = e >> 3, d0 = (e & 7) * 8;
            size_t goff = (rowbase + kv0 + r) * QKV_N + D_MODEL + h * HDIM + d0;
            u16x8 kk = *(const u16x8*)(qkv + goff);
            *(u16x8*)(&Ks[r * 72 + d0]) = kk;
        }
        // V staging: 128 threads x 4 rows -> transposed via register repack
        if (tid < 128) {
            int r0 = (tid & 15) * 4, d0v = (tid >> 4) * 8;
            const unsigned short* vp = qkv + (rowbase + kv0 + r0) * QKV_N
                                       + 2 * D_MODEL + h * HDIM + d0v;
            u16x8 w0 = *(const u16x8*)vp;
            u16x8 w1 = *(const u16x8*)(vp + QKV_N);
            u16x8 w2 = *(const u16x8*)(vp + 2 * QKV_N);
            u16x8 w3 = *(const u16x8*)(vp + 3 * QKV_N);
#pragma unroll
            for (int j = 0; j < 8; j++) {
                unsigned long long pk = (unsigned long long)w0[j]
                    | ((unsigned long long)w1[j] << 16)
                    | ((unsigned long long)w2[j] << 32)
                    | ((unsigned long long)w3[j] << 48);
                *(unsigned long long*)(&Vs[(d0v + j) * 72 + r0]) = pk;
            }
        }
        __syncthreads();

        if (kt <= p) update(qAf0, qAf1, oaA, mjA, ljA, qA0, kv0);  // block-uniform
        update(qBf0, qBf1, oaB, mjB, ljB, qB0, kv0);
    }

#pragma unroll
    for (int di = 0; di < 4; di++)
#pragma unroll
        for (int j = 0; j < 4; j++) {
            int rowA = qA0 + wid * 16 + lhi * 4 + j;
            ctxb[(rowbase + rowA) * D_MODEL + h * HDIM + di * 16 + l16] =
                f2bf(oaA[di][j] / ljA[j]);
            int rowB = qB0 + wid * 16 + lhi * 4 + j;
            ctxb[(rowbase + rowB) * D_MODEL + h * HDIM + di * 16 + l16] =
                f2bf(oaB[di][j] / ljB[j]);
        }
}

// ------- fused residual(xb + p0 + p1) + LayerNorm, bf16 in-place residual -------
__global__ __launch_bounds__(256) void ln3(
    unsigned short* __restrict__ xb, const unsigned short* __restrict__ p0,
    const unsigned short* __restrict__ p1,
    const float* __restrict__ sc, const float* __restrict__ bi)
{
    const int row = blockIdx.x;
    const int t = threadIdx.x;
    const size_t base = (size_t)row * D_MODEL + t * 4;
    ushort4 xu = *(const ushort4*)(xb + base);
    ushort4 au = *(const ushort4*)(p0 + base);
    ushort4 bu = *(const ushort4*)(p1 + base);
    float v0 = bf2f(xu.x) + bf2f(au.x) + bf2f(bu.x);
    float v1 = bf2f(xu.y) + bf2f(au.y) + bf2f(bu.y);
    float v2 = bf2f(xu.z) + bf2f(au.z) + bf2f(bu.z);
    float v3 = bf2f(xu.w) + bf2f(au.w) + bf2f(bu.w);
    float sum = v0 + v1 + v2 + v3;
    float sq  = v0 * v0 + v1 * v1 + v2 * v2 + v3 * v3;
#pragma unroll
    for (int off = 1; off < 64; off <<= 1) {
        sum += __shfl_xor(sum, off);
        sq  += __shfl_xor(sq, off);
    }
    __shared__ float red[8];
    int wid = t >> 6, lane = t & 63;
    if (lane == 0) { red[wid] = sum; red[4 + wid] = sq; }
    __syncthreads();
    sum = red[0] + red[1] + red[2] + red[3];
    sq  = red[4] + red[5] + red[6] + red[7];
    float mu   = sum * (1.f / D_MODEL);
    float var  = sq * (1.f / D_MODEL) - mu * mu;
    float rstd = rsqrtf(var + LN_EPS);
    int c = t * 4;
    float4 sv = *(const float4*)(sc + c);
    float4 bv = *(const float4*)(bi + c);
    float y0 = sv.x * (v0 - mu) * rstd + bv.x;
    float y1 = sv.y * (v1 - mu) * rstd + bv.y;
    float y2 = sv.z * (v2 - mu) * rstd + bv.z;
    float y3 = sv.w * (v3 - mu) * rstd + bv.w;
    unsigned long long pk = (unsigned long long)f2bf(y0)
        | ((unsigned long long)f2bf(y1) << 16)
        | ((unsigned long long)f2bf(y2) << 32)
        | ((unsigned long long)f2bf(y3) << 48);
    *(unsigned long long*)(xb + base) = pk;
}

// ------- ln5: residual(xb + 4 partials) + LayerNorm (for split-K=4 FFN2) -------
__global__ __launch_bounds__(256) void ln5(
    unsigned short* __restrict__ xb, const unsigned short* __restrict__ p,
    const float* __restrict__ sc, const float* __restrict__ bi)
{
    const int row = blockIdx.x;
    const int t = threadIdx.x;
    const size_t base = (size_t)row * D_MODEL + t * 4;
    const size_t stride = (size_t)ROWS * D_MODEL;
    ushort4 xu = *(const ushort4*)(xb + base);
    float v0 = bf2f(xu.x), v1 = bf2f(xu.y), v2 = bf2f(xu.z), v3 = bf2f(xu.w);
#pragma unroll
    for (int k = 0; k < 4; k++) {
        ushort4 pu = *(const ushort4*)(p + k * stride + base);
        v0 += bf2f(pu.x); v1 += bf2f(pu.y); v2 += bf2f(pu.z); v3 += bf2f(pu.w);
    }
    float sum = v0 + v1 + v2 + v3;
    float sq  = v0 * v0 + v1 * v1 + v2 * v2 + v3 * v3;
#pragma unroll
    for (int off = 1; off < 64; off <<= 1) {
        sum += __shfl_xor(sum, off);
        sq  += __shfl_xor(sq, off);
    }
    __shared__ float red[8];
    int wid = t >> 6, lane = t & 63;
    if (lane == 0) { red[wid] = sum; red[4 + wid] = sq; }
    __syncthreads();
    sum = red[0] + red[1] + red[2] + red[3];
    sq  = red[4] + red[5] + red[6] + red[7];
    float mu   = sum * (1.f / D_MODEL);
    float var  = sq * (1.f / D_MODEL) - mu * mu;
    float rstd = rsqrtf(var + LN_EPS);
    int c = t * 4;
    float4 sv = *(const float4*)(sc + c);
    float4 bv = *(const float4*)(bi + c);
    float y0 = sv.x * (v0 - mu) * rstd + bv.x;
    float y1 = sv.y * (v1 - mu) * rstd + bv.y;
    float y2 = sv.z * (v2 - mu) * rstd + bv.z;
    float y3 = sv.w * (v3 - mu) * rstd + bv.w;
    unsigned long long pk = (unsigned long long)f2bf(y0)
        | ((unsigned long long)f2bf(y1) << 16)
        | ((unsigned long long)f2bf(y2) << 32)
        | ((unsigned long long)f2bf(y3) << 48);
    *(unsigned long long*)(xb + base) = pk;
}

// ---------------- launcher ----------------
extern "C" void kernel_launch(void* const* d_in, const int* in_sizes, int n_in,
                              void* d_out, int out_size, void* d_ws, size_t ws_size,
                              hipStream_t stream)
{
    (void)in_sizes; (void)n_in; (void)out_size;
    const int*   tokens = (const int*)d_in[0];
    const float* emb  = (const float*)d_in[2];
    const float* pose = (const float*)d_in[3];
    const float* Wq = (const float*)d_in[4];
    const float* bq = (const float*)d_in[5];
    const float* Wk = (const float*)d_in[6];
    const float* bk = (const float*)d_in[7];
    const float* Wv = (const float*)d_in[8];
    const float* bv = (const float*)d_in[9];
    const float* Wo = (const float*)d_in[10];
    const float* bo = (const float*)d_in[11];
    const float* n1s = (const float*)d_in[12];
    const float* n1b = (const float*)d_in[13];
    const float* W1 = (const float*)d_in[14];
    const float* b1 = (const float*)d_in[15];
    const float* W2 = (const float*)d_in[16];
    const float* b2 = (const float*)d_in[17];
    const float* n2s = (const float*)d_in[18];
    const float* n2b = (const float*)d_in[19];

    char* w = (char*)d_ws;
    size_t off = 0;
    auto carve = [&](size_t bytes) -> void* {
        void* p = w + off;
        off = (off + bytes + 255) & ~(size_t)255;
        return p;
    };
    unsigned short* tmp = (unsigned short*)carve((size_t)4 * ROWS * D_MODEL * 2);  // 4 bf16 partials
    unsigned short* xb    = (unsigned short*)carve((size_t)ROWS * D_MODEL * 2);   // bf16 residual
    unsigned short* qkvb  = (unsigned short*)carve((size_t)ROWS * QKV_N * 2);
    unsigned short* cbuf  = (unsigned short*)carve((size_t)ROWS * D_MODEL * 2);
    unsigned short* hbuf  = (unsigned short*)carve((size_t)ROWS * FF_DIM * 2);
    unsigned short* wt = (unsigned short*)carve((size_t)12 * 1048576 * 2);  // per-layer fused (24MB)
    float* bqkv = (float*)carve((size_t)NLAYER * QKV_N * 4);
    unsigned short* embb = qkvb;   // tied-head emb aliases dead qkv/ctx/h region
    unsigned short* tmp1 = tmp + (size_t)ROWS * D_MODEL;
    if (off > ws_size) return;

    bias3_k<<<NLAYER * 3, 256, 0, stream>>>(bq, bk, bv, bqkv);
    embed_k<<<ROWS, 256, 0, stream>>>(tokens, emb, pose, xb);

    for (int l = 0; l < NLAYER; l++) {
        unsigned short* wtQKV = wt;
        unsigned short* wtWo  = wt + (size_t)3 * 1048576;
        unsigned short* wtW1  = wt + (size_t)4 * 1048576;
        unsigned short* wtW2  = wt + (size_t)8 * 1048576;

        transpose_all<<<3072, 256, 0, stream>>>(
            Wq + (size_t)l * D_MODEL * D_MODEL, Wk + (size_t)l * D_MODEL * D_MODEL,
            Wv + (size_t)l * D_MODEL * D_MODEL, Wo + (size_t)l * D_MODEL * D_MODEL,
            W1 + (size_t)l * D_MODEL * FF_DIM,  W2 + (size_t)l * FF_DIM * D_MODEL, wt);

        gemm_bt<1><<<dim3(768, 1), 256, 0, stream>>>(xb, D_MODEL, wtQKV, D_MODEL,
                                                     bqkv + (size_t)l * QKV_N, qkvb, QKV_N, D_MODEL);

        attn_fwd<<<dim3(8, BATCH * NHEAD), 256, 0, stream>>>(qkvb, cbuf);

        gemm_bt<1><<<dim3(256, 2), 256, 0, stream>>>(cbuf, D_MODEL, wtWo, D_MODEL,
                                                     bo + (size_t)l * D_MODEL, tmp, D_MODEL, D_MODEL / 2);
        ln3<<<ROWS, 256, 0, stream>>>(xb, tmp, tmp1, n1s + (size_t)l * D_MODEL, n1b + (size_t)l * D_MODEL);

        gemm256<2, 1><<<dim3((FF_DIM / 256) * 16, 1), 512, 0, stream>>>(
            xb, D_MODEL, wtW1, D_MODEL, b1 + (size_t)l * FF_DIM, hbuf, FF_DIM, D_MODEL);
        // FFN2: gemm256 split-K=4 -> 64 x 4 = 256 blocks (one full round)
        gemm256<1, 1><<<dim3((D_MODEL / 256) * 16, 4), 512, 0, stream>>>(
            hbuf, FF_DIM, wtW2, FF_DIM, b2 + (size_t)l * D_MODEL, tmp, D_MODEL, FF_DIM / 4);
        ln5<<<ROWS, 256, 0, stream>>>(xb, tmp, n2s + (size_t)l * D_MODEL, n2b + (size_t)l * D_MODEL);
    }

    cast_bf<<<(VOCAB * D_MODEL) / 1024, 256, 0, stream>>>(emb, embb, (size_t)VOCAB * D_MODEL);
    // head: NO XCD swizzle — bm-fastest order shares B panels via L3
    gemm256<0, 0><<<dim3((VOCAB / 256) * 16, 1), 512, 0, stream>>>(
        xb, D_MODEL, embb, D_MODEL, nullptr, d_out, VOCAB, D_MODEL);
}

// Round 15
// 1958.355 us; speedup vs baseline: 1.0865x; 1.0055x over previous
//
#include <hip/hip_runtime.h>

#define D_MODEL 1024
#define SEQ     1024
#define BATCH   4
#define NHEAD   16
#define HDIM    64
#define FF_DIM  4096
#define NLAYER  8
#define VOCAB   32000
#define ROWS    (BATCH*SEQ)
#define QKV_N   3072
#define LN_EPS  1e-5f

typedef __attribute__((ext_vector_type(4))) float   f32x4;
typedef __attribute__((ext_vector_type(8))) unsigned short u16x8;
typedef __attribute__((ext_vector_type(8))) __bf16  bf16x8;

typedef const unsigned int __attribute__((address_space(1)))* gas_t;
typedef unsigned int __attribute__((address_space(3)))* las_t;

__device__ __forceinline__ void gld16(const void* g, void* l) {
    __builtin_amdgcn_global_load_lds((gas_t)g, (las_t)l, 16, 0, 0);
}

__device__ __forceinline__ unsigned short f2bf(float f) {
    unsigned int u = __builtin_bit_cast(unsigned int, f);
    u += 0x7FFFu + ((u >> 16) & 1u);   // RNE
    return (unsigned short)(u >> 16);
}

__device__ __forceinline__ float bf2f(unsigned short u) {
    return __builtin_bit_cast(float, (unsigned int)u << 16);
}

__device__ __forceinline__ f32x4 mfma32(u16x8 a, u16x8 b, f32x4 c) {
    return __builtin_amdgcn_mfma_f32_16x16x32_bf16(
        __builtin_bit_cast(bf16x8, a), __builtin_bit_cast(bf16x8, b), c, 0, 0, 0);
}

// ---------------- embed: xb = bf16(emb[tok] + pos) ----------------
__global__ __launch_bounds__(256) void embed_k(
    const int* __restrict__ tok, const float* __restrict__ emb,
    const float* __restrict__ pos, unsigned short* __restrict__ xb)
{
    int bs = blockIdx.x;
    int s  = bs & (SEQ - 1);
    int tk = tok[bs];
    int c  = threadIdx.x * 4;
    float4 e = *(const float4*)(emb + (size_t)tk * D_MODEL + c);
    float4 p = *(const float4*)(pos + (size_t)s * D_MODEL + c);
    float y0 = e.x + p.x, y1 = e.y + p.y, y2 = e.z + p.z, y3 = e.w + p.w;
    size_t base = (size_t)bs * D_MODEL + c;
    unsigned long long pk = (unsigned long long)f2bf(y0)
        | ((unsigned long long)f2bf(y1) << 16)
        | ((unsigned long long)f2bf(y2) << 32)
        | ((unsigned long long)f2bf(y3) << 48);
    *(unsigned long long*)(xb + base) = pk;
}

// ---------------- cast fp32 -> bf16 ----------------
__global__ __launch_bounds__(256) void cast_bf(
    const float* __restrict__ in, unsigned short* __restrict__ out, size_t n)
{
    size_t i = ((size_t)blockIdx.x * 256 + threadIdx.x) * 4;
    if (i >= n) return;
    float4 v = *(const float4*)(in + i);
    unsigned long long pk = (unsigned long long)f2bf(v.x)
        | ((unsigned long long)f2bf(v.y) << 16)
        | ((unsigned long long)f2bf(v.z) << 32)
        | ((unsigned long long)f2bf(v.w) << 48);
    *(unsigned long long*)(out + i) = pk;
}

// ---------------- concat qkv biases ----------------
__global__ __launch_bounds__(256) void bias3_k(
    const float* __restrict__ bq, const float* __restrict__ bk,
    const float* __restrict__ bv, float* __restrict__ out)
{
    int l = blockIdx.x / 3, which = blockIdx.x % 3;
    const float* src = which == 0 ? bq : (which == 1 ? bk : bv);
    int i = threadIdx.x * 4;
    float4 v = *(const float4*)(src + (size_t)l * D_MODEL + i);
    *(float4*)(out + (size_t)l * QKV_N + which * D_MODEL + i) = v;
}

// ---------------- transpose tile body (shared) ----------------
__device__ __forceinline__ void tc_tile(
    const float* __restrict__ W, unsigned short* __restrict__ Wt,
    int K, int N, int n0, int k0)
{
    __shared__ float t[64][65];
    int rr = threadIdx.x >> 4;          // 0..15
    int cc = (threadIdx.x & 15) * 4;    // 0..60
#pragma unroll
    for (int it = 0; it < 4; it++) {
        int r = it * 16 + rr;
        float4 v = *(const float4*)(W + (size_t)(k0 + r) * N + n0 + cc);
        t[r][cc] = v.x; t[r][cc + 1] = v.y; t[r][cc + 2] = v.z; t[r][cc + 3] = v.w;
    }
    __syncthreads();
#pragma unroll
    for (int it = 0; it < 4; it++) {
        int n = it * 16 + rr;
        unsigned long long pk = (unsigned long long)f2bf(t[cc][n])
            | ((unsigned long long)f2bf(t[cc + 1][n]) << 16)
            | ((unsigned long long)f2bf(t[cc + 2][n]) << 32)
            | ((unsigned long long)f2bf(t[cc + 3][n]) << 48);
        *(unsigned long long*)(Wt + (size_t)(n0 + n) * K + k0 + cc) = pk;
    }
}

// ---------------- per-layer fused transpose: Wq,Wk,Wv,Wo,W1,W2 in ONE launch ----
// wt layout (elems): [0,3M) qkv^T, [3M,4M) Wo^T, [4M,8M) W1^T, [8M,12M) W2^T
__global__ __launch_bounds__(256) void transpose_all(
    const float* __restrict__ Wq, const float* __restrict__ Wk,
    const float* __restrict__ Wv, const float* __restrict__ Wo,
    const float* __restrict__ W1, const float* __restrict__ W2,
    unsigned short* __restrict__ wt)
{
    int b = blockIdx.x;
    const float* W; unsigned short* out; int K, N, t;
    if (b < 768)       { int w = b >> 8; t = b & 255; W = w == 0 ? Wq : (w == 1 ? Wk : Wv);
                         out = wt + (size_t)w * 1048576; K = 1024; N = 1024; }
    else if (b < 1024) { t = b - 768;  W = Wo; out = wt + (size_t)3 * 1048576; K = 1024; N = 1024; }
    else if (b < 2048) { t = b - 1024; W = W1; out = wt + (size_t)4 * 1048576; K = 1024; N = 4096; }
    else               { t = b - 2048; W = W2; out = wt + (size_t)8 * 1048576; K = 4096; N = 1024; }
    int ntx = N >> 6;
    tc_tile(W, out, K, N, (t % ntx) * 64, (t / ntx) * 64);
}

// ---------------- small NT GEMM (m97 128x128) with split-K support ----------------
// MODE 1: bf16 out; MODE 2: relu->bf16 out.
template<int MODE>
__global__ __launch_bounds__(256, 3) void gemm_bt(
    const unsigned short* __restrict__ A, int lda,
    const unsigned short* __restrict__ Bt, int ldb,
    const float* __restrict__ bias, void* __restrict__ Cout, int N, int Klen)
{
    __shared__ unsigned short As[128 * 32];
    __shared__ unsigned short Bs[128 * 32];
    const int part = blockIdx.y;
    A  += (size_t)part * Klen;
    Bt += (size_t)part * Klen;
    int flat = blockIdx.x;
    const int bm = flat & 31, bn = flat >> 5;
    const int tid  = threadIdx.x;
    const int wid  = tid >> 6, lane = tid & 63;
    const int l16  = lane & 15, lhi = lane >> 4;
    const int wr   = wid >> 1, wc = wid & 1;

    const int srow = wid * 32 + (lane >> 2);
    const int scol = (lane & 3) * 8;
    const unsigned short* gA0 = A  + ((size_t)bm * 128 + srow) * lda + scol;
    const unsigned short* gB0 = Bt + ((size_t)bn * 128 + srow) * ldb + scol;
    unsigned short* lA = As + wid * 32 * 32;
    unsigned short* lB = Bs + wid * 32 * 32;

    f32x4 acc[4][4];
#pragma unroll
    for (int i = 0; i < 4; i++)
#pragma unroll
        for (int j = 0; j < 4; j++) acc[i][j] = (f32x4){0.f, 0.f, 0.f, 0.f};

    for (int k0 = 0; k0 < Klen; k0 += 32) {
        __syncthreads();
        gld16(gA0 + k0,                    lA);
        gld16(gA0 + k0 + 16 * (size_t)lda, lA + 16 * 32);
        gld16(gB0 + k0,                    lB);
        gld16(gB0 + k0 + 16 * (size_t)ldb, lB + 16 * 32);
        __syncthreads();
        u16x8 af[4], bfr[4];
#pragma unroll
        for (int i = 0; i < 4; i++)
            af[i] = *(const u16x8*)(As + (wr * 64 + i * 16 + l16) * 32 + lhi * 8);
#pragma unroll
        for (int i = 0; i < 4; i++)
            bfr[i] = *(const u16x8*)(Bs + (wc * 64 + i * 16 + l16) * 32 + lhi * 8);
#pragma unroll
        for (int mi = 0; mi < 4; mi++)
#pragma unroll
            for (int ni = 0; ni < 4; ni++)
                acc[mi][ni] = mfma32(af[mi], bfr[ni], acc[mi][ni]);
    }

    const size_t pofs = (size_t)part * (size_t)ROWS * N;
    // epilogue: j-then-ni order so 4 stores cover 128B contiguous per row
#pragma unroll
    for (int mi = 0; mi < 4; mi++) {
        float bv[4];
#pragma unroll
        for (int ni = 0; ni < 4; ni++)
            bv[ni] = (bias && part == 0) ? bias[bn * 128 + wc * 64 + ni * 16 + l16] : 0.f;
#pragma unroll
        for (int j = 0; j < 4; j++) {
            int row = bm * 128 + wr * 64 + mi * 16 + lhi * 4 + j;
#pragma unroll
            for (int ni = 0; ni < 4; ni++) {
                int col = bn * 128 + wc * 64 + ni * 16 + l16;
                float v = acc[mi][ni][j] + bv[ni];
                size_t idx = pofs + (size_t)row * N + col;
                if constexpr (MODE == 1) {
                    ((unsigned short*)Cout)[idx] = f2bf(v);
                } else {
                    ((unsigned short*)Cout)[idx] = f2bf(v > 0.f ? v : 0.f);
                }
            }
        }
    }
}

// ====== 256x256 8-phase GEMM (R4-best structure + NT store), split-K capable ======
#define PSYNC() do { __builtin_amdgcn_s_barrier(); \
    asm volatile("s_waitcnt lgkmcnt(0)" ::: "memory"); \
    __builtin_amdgcn_sched_barrier(0); } while (0)
#define PEND() __builtin_amdgcn_s_barrier()
#define VM4()  asm volatile("s_waitcnt vmcnt(4)" ::: "memory")

#define LOADA(reg, half) do { \
    _Pragma("unroll") \
    for (int m_ = 0; m_ < 4; m_++) { \
        aF[m_][0] = *(const u16x8*)((reg) + ((half)*4 + m_) * 2048 + lane0); \
        aF[m_][1] = *(const u16x8*)((reg) + ((half)*4 + m_) * 2048 + lane1); \
    } } while (0)

#define LOADB(reg, np) do { \
    _Pragma("unroll") \
    for (int n_ = 0; n_ < 2; n_++) { \
        bF[(np)*2 + n_][0] = *(const u16x8*)((reg) + ((np)*2 + n_) * 2048 + lane0); \
        bF[(np)*2 + n_][1] = *(const u16x8*)((reg) + ((np)*2 + n_) * 2048 + lane1); \
    } } while (0)

#define MFMA8(ma, np) do { \
    __builtin_amdgcn_s_setprio(1); \
    _Pragma("unroll") \
    for (int m_ = 0; m_ < 4; m_++) \
        _Pragma("unroll") \
        for (int n_ = 0; n_ < 2; n_++) { \
            acc[(ma)+m_][(np)*2+n_] = mfma32(aF[m_][0], bF[(np)*2+n_][0], acc[(ma)+m_][(np)*2+n_]); \
            acc[(ma)+m_][(np)*2+n_] = mfma32(aF[m_][1], bF[(np)*2+n_][1], acc[(ma)+m_][(np)*2+n_]); \
        } \
    __builtin_amdgcn_s_setprio(0); \
} while (0)

template<int MODE, int SWZ>
__global__ __launch_bounds__(512, 2) void gemm256(
    const unsigned short* __restrict__ A, int lda,
    const unsigned short* __restrict__ Bt, int ldb,
    const float* __restrict__ bias, void* __restrict__ Cout, int N, int Klen)
{
    __shared__ unsigned short lds[65536] __attribute__((aligned(128)));
    const int tid = threadIdx.x, wid = tid >> 6, lane = tid & 63;
    const int l16 = lane & 15, lhi = lane >> 4;
    const int wr = wid >> 2, wc = wid & 3;

    const int part = blockIdx.y;
    A  += (size_t)part * Klen;
    Bt += (size_t)part * Klen;

    int flat = blockIdx.x;
    if constexpr (SWZ) {
        int cpx = gridDim.x >> 3; flat = (flat & 7) * cpx + (flat >> 3);
    }
    const int bm = flat & 15, bn = flat >> 4;
    const int NT = Klen >> 6;

    const int srowL = tid >> 3;                                      // 0..63
    const int scolb = ((tid & 7) << 4) ^ (((tid >> 3) & 7) << 4);    // bytes (pre-swz src)
    const unsigned short* baseA = A  + (size_t)(bm * 256 + srowL) * lda + (scolb >> 1);
    const unsigned short* baseB = Bt + (size_t)(bn * 256 + srowL) * ldb + (scolb >> 1);
    unsigned short* dst0 = lds + wid * 512;   // wave-uniform; HW adds lane*16B

    auto stage = [&](int isB, int tile, int h) {   // one half-tile = 2 gld16
        const size_t ld = isB ? (size_t)ldb : (size_t)lda;
        const unsigned short* s = (isB ? baseB : baseA) + (size_t)(h * 128) * ld + (size_t)tile * 64;
        unsigned short* d = dst0 + (tile & 1) * 32768 + isB * 16384 + h * 8192;
        gld16(s, d);
        gld16(s + 64 * ld, d + 4096);
    };

    const int lswz  = (l16 & 7) << 4;
    const int lane0 = ((lhi * 16) ^ lswz) + l16 * 128;
    const int lane1 = ((64 + lhi * 16) ^ lswz) + l16 * 128;

    const char* aR0 = (const char*)lds + wr * 16384;
    const char* bR0 = (const char*)lds + 32768 + (wc >> 1) * 16384 + (wc & 1) * 8192;
    const char* aR1 = aR0 + 65536;
    const char* bR1 = bR0 + 65536;

    f32x4 acc[8][4];
#pragma unroll
    for (int i = 0; i < 8; i++)
#pragma unroll
        for (int j = 0; j < 4; j++) acc[i][j] = (f32x4){0.f, 0.f, 0.f, 0.f};
    u16x8 aF[4][2], bF[4][2];

    // prologue: B(0),A(0),B(1); leave B(1)'s 4 loads in flight
    stage(1, 0, 0); stage(1, 0, 1);
    stage(0, 0, 0); stage(0, 0, 1);
    stage(1, 1, 0); stage(1, 1, 1);
    VM4();
    __builtin_amdgcn_s_barrier();

    for (int t = 0; t < NT; t += 2) {
        const bool more = (t + 2) < NT;
        // ---- K-tile t (buf0) ----
        LOADA(aR0, 0); LOADB(bR0, 0); stage(0, t + 1, 0);
        PSYNC(); MFMA8(0, 0); PEND();
        LOADB(bR0, 1);                stage(0, t + 1, 1);
        PSYNC(); MFMA8(0, 1); PEND();
        LOADA(aR0, 1);                if (more) stage(1, t + 2, 0);
        PSYNC(); MFMA8(4, 0); PEND();
        if (more) { stage(1, t + 2, 1); VM4(); }
        else      { asm volatile("s_waitcnt vmcnt(0)" ::: "memory"); }
        PSYNC(); MFMA8(4, 1); PEND();
        // ---- K-tile t+1 (buf1) ----
        LOADA(aR1, 0); LOADB(bR1, 0); if (more) stage(0, t + 2, 0);
        PSYNC(); MFMA8(0, 0); PEND();
        LOADB(bR1, 1);                if (more) stage(0, t + 2, 1);
        PSYNC(); MFMA8(0, 1); PEND();
        LOADA(aR1, 1);                if (more) stage(1, t + 3, 0);
        PSYNC(); MFMA8(4, 0); PEND();
        if (more) { stage(1, t + 3, 1); VM4(); }
        PSYNC(); MFMA8(4, 1); PEND();
    }

    const size_t pofs = (size_t)part * (size_t)ROWS * N;
    // epilogue: j-then-ni order -> 4 consecutive stores cover one full line
#pragma unroll
    for (int mi = 0; mi < 8; mi++) {
        float bv[4];
#pragma unroll
        for (int ni = 0; ni < 4; ni++)
            bv[ni] = (bias && part == 0) ? bias[bn * 256 + wc * 64 + ni * 16 + l16] : 0.f;
#pragma unroll
        for (int j = 0; j < 4; j++) {
            int row = bm * 256 + wr * 128 + mi * 16 + lhi * 4 + j;
#pragma unroll
            for (int ni = 0; ni < 4; ni++) {
                int col = bn * 256 + wc * 64 + ni * 16 + l16;
                float v = acc[mi][ni][j] + bv[ni];
                size_t idx = pofs + (size_t)row * N + col;
                if constexpr (MODE == 0) {
                    __builtin_nontemporal_store(v, (float*)Cout + idx);
                } else if constexpr (MODE == 1) {
                    ((unsigned short*)Cout)[idx] = f2bf(v);
                } else {
                    ((unsigned short*)Cout)[idx] = f2bf(v > 0.f ? v : 0.f);
                }
            }
        }
    }
}

// ---------------- flash attention (causal), PAIRED q-tiles for triangle balance ----
__global__ __launch_bounds__(256, 3) void attn_fwd(
    const unsigned short* __restrict__ qkv, unsigned short* __restrict__ ctxb)
{
    __shared__ unsigned short Ks[64 * 72];
    __shared__ unsigned short Vs[64 * 72];   // transposed: Vs[d][kv]
    __shared__ unsigned short Ps[4 * 16 * 72];
    const int tid = threadIdx.x;
    const int wid = tid >> 6, lane = tid & 63;
    const int l16 = lane & 15, lhi = lane >> 4;
    const int bh  = blockIdx.y, b = bh >> 4, h = bh & 15;
    const int p   = blockIdx.x;          // 0..7
    const int qA0 = p * 64;
    const int qB0 = (15 - p) * 64;
    const size_t rowbase = (size_t)b * SEQ;

    const unsigned short* qpA = qkv + (rowbase + qA0 + wid * 16 + l16) * QKV_N + h * HDIM + lhi * 8;
    u16x8 qAf0 = *(const u16x8*)qpA;
    u16x8 qAf1 = *(const u16x8*)(qpA + 32);
    const unsigned short* qpB = qkv + (rowbase + qB0 + wid * 16 + l16) * QKV_N + h * HDIM + lhi * 8;
    u16x8 qBf0 = *(const u16x8*)qpB;
    u16x8 qBf1 = *(const u16x8*)(qpB + 32);

    f32x4 oaA[4], oaB[4];
    float mjA[4], ljA[4], mjB[4], ljB[4];
#pragma unroll
    for (int i = 0; i < 4; i++) {
        oaA[i] = (f32x4){0.f, 0.f, 0.f, 0.f};
        oaB[i] = (f32x4){0.f, 0.f, 0.f, 0.f};
        mjA[i] = -1e30f; ljA[i] = 0.f;
        mjB[i] = -1e30f; ljB[i] = 0.f;
    }

    auto update = [&](u16x8 qf0, u16x8 qf1, f32x4 (&oa)[4],
                      float (&mj)[4], float (&lj)[4], int q0, int kv0) {
        f32x4 sa[4];
        __builtin_amdgcn_s_setprio(1);
#pragma unroll
        for (int ni = 0; ni < 4; ni++) {
            f32x4 z = (f32x4){0.f, 0.f, 0.f, 0.f};
            u16x8 k0f = *(const u16x8*)(&Ks[(ni * 16 + l16) * 72 + lhi * 8]);
            u16x8 k1f = *(const u16x8*)(&Ks[(ni * 16 + l16) * 72 + 32 + lhi * 8]);
            z = mfma32(qf0, k0f, z);
            z = mfma32(qf1, k1f, z);
            sa[ni] = z;
        }
        __builtin_amdgcn_s_setprio(0);
        float tm[4] = {-1e30f, -1e30f, -1e30f, -1e30f};
#pragma unroll
        for (int ni = 0; ni < 4; ni++)
#pragma unroll
            for (int j = 0; j < 4; j++) {
                float v = sa[ni][j] * 0.125f;
                int row = q0 + wid * 16 + lhi * 4 + j;
                int col = kv0 + ni * 16 + l16;
                if (col > row) v = -1e30f;
                sa[ni][j] = v;
                tm[j] = fmaxf(tm[j], v);
            }
#pragma unroll
        for (int j = 0; j < 4; j++) {
#pragma unroll
            for (int off = 1; off < 16; off <<= 1)
                tm[j] = fmaxf(tm[j], __shfl_xor(tm[j], off));
        }
        float al[4], rs[4] = {0.f, 0.f, 0.f, 0.f};
#pragma unroll
        for (int j = 0; j < 4; j++) {
            float mn = fmaxf(mj[j], tm[j]);
            al[j] = __expf(mj[j] - mn);
            mj[j] = mn;
        }
#pragma unroll
        for (int ni = 0; ni < 4; ni++)
#pragma unroll
            for (int j = 0; j < 4; j++) {
                float pv = __expf(sa[ni][j] - mj[j]);
                rs[j] += pv;
                Ps[wid * 1152 + (lhi * 4 + j) * 72 + ni * 16 + l16] = f2bf(pv);
            }
#pragma unroll
        for (int j = 0; j < 4; j++) {
#pragma unroll
            for (int off = 1; off < 16; off <<= 1)
                rs[j] += __shfl_xor(rs[j], off);
            lj[j] = lj[j] * al[j] + rs[j];
        }
#pragma unroll
        for (int di = 0; di < 4; di++)
#pragma unroll
            for (int j = 0; j < 4; j++) oa[di][j] *= al[j];
        __builtin_amdgcn_s_setprio(1);
#pragma unroll
        for (int di = 0; di < 4; di++) {
#pragma unroll
            for (int kc = 0; kc < 2; kc++) {
                u16x8 pf = *(const u16x8*)(&Ps[wid * 1152 + l16 * 72 + kc * 32 + lhi * 8]);
                u16x8 vf = *(const u16x8*)(&Vs[(di * 16 + l16) * 72 + kc * 32 + lhi * 8]);
                oa[di] = mfma32(pf, vf, oa[di]);
            }
        }
        __builtin_amdgcn_s_setprio(0);
    };

    const int ntB = 16 - p;   // kv tiles 0..15-p (covers both q-tiles)
    for (int kt = 0; kt < ntB; ++kt) {
        const int kv0 = kt * 64;
        __syncthreads();
        // K staging: vector writes, row-major
#pragma unroll
        for (int it = 0; it < 2; ++it) {
            int e = it * 256 + tid;
            int r = e >> 3, d0 = (e & 7) * 8;
            size_t goff = (rowbase + kv0 + r) * QKV_N + D_MODEL + h * HDIM + d0;
            u16x8 kk = *(const u16x8*)(qkv + goff);
            *(u16x8*)(&Ks[r * 72 + d0]) = kk;
        }
        // V staging: 128 threads x 4 rows -> transposed via register repack
        if (tid < 128) {
            int r0 = (tid & 15) * 4, d0v = (tid >> 4) * 8;
            const unsigned short* vp = qkv + (rowbase + kv0 + r0) * QKV_N
                                       + 2 * D_MODEL + h * HDIM + d0v;
            u16x8 w0 = *(const u16x8*)vp;
            u16x8 w1 = *(const u16x8*)(vp + QKV_N);
            u16x8 w2 = *(const u16x8*)(vp + 2 * QKV_N);
            u16x8 w3 = *(const u16x8*)(vp + 3 * QKV_N);
#pragma unroll
            for (int j = 0; j < 8; j++) {
                unsigned long long pk = (unsigned long long)w0[j]
                    | ((unsigned long long)w1[j] << 16)
                    | ((unsigned long long)w2[j] << 32)
                    | ((unsigned long long)w3[j] << 48);
                *(unsigned long long*)(&Vs[(d0v + j) * 72 + r0]) = pk;
            }
        }
        __syncthreads();

        if (kt <= p) update(qAf0, qAf1, oaA, mjA, ljA, qA0, kv0);  // block-uniform
        update(qBf0, qBf1, oaB, mjB, ljB, qB0, kv0);
    }

#pragma unroll
    for (int di = 0; di < 4; di++)
#pragma unroll
        for (int j = 0; j < 4; j++) {
            int rowA = qA0 + wid * 16 + lhi * 4 + j;
            ctxb[(rowbase + rowA) * D_MODEL + h * HDIM + di * 16 + l16] =
                f2bf(oaA[di][j] / ljA[j]);
            int rowB = qB0 + wid * 16 + lhi * 4 + j;
            ctxb[(rowbase + rowB) * D_MODEL + h * HDIM + di * 16 + l16] =
                f2bf(oaB[di][j] / ljB[j]);
        }
}

// ------- fused residual(xb + p0 + p1) + LayerNorm, bf16 in-place residual -------
__global__ __launch_bounds__(256) void ln3(
    unsigned short* __restrict__ xb, const unsigned short* __restrict__ p0,
    const unsigned short* __restrict__ p1,
    const float* __restrict__ sc, const float* __restrict__ bi)
{
    const int row = blockIdx.x;
    const int t = threadIdx.x;
    const size_t base = (size_t)row * D_MODEL + t * 4;
    ushort4 xu = *(const ushort4*)(xb + base);
    ushort4 au = *(const ushort4*)(p0 + base);
    ushort4 bu = *(const ushort4*)(p1 + base);
    float v0 = bf2f(xu.x) + bf2f(au.x) + bf2f(bu.x);
    float v1 = bf2f(xu.y) + bf2f(au.y) + bf2f(bu.y);
    float v2 = bf2f(xu.z) + bf2f(au.z) + bf2f(bu.z);
    float v3 = bf2f(xu.w) + bf2f(au.w) + bf2f(bu.w);
    float sum = v0 + v1 + v2 + v3;
    float sq  = v0 * v0 + v1 * v1 + v2 * v2 + v3 * v3;
#pragma unroll
    for (int off = 1; off < 64; off <<= 1) {
        sum += __shfl_xor(sum, off);
        sq  += __shfl_xor(sq, off);
    }
    __shared__ float red[8];
    int wid = t >> 6, lane = t & 63;
    if (lane == 0) { red[wid] = sum; red[4 + wid] = sq; }
    __syncthreads();
    sum = red[0] + red[1] + red[2] + red[3];
    sq  = red[4] + red[5] + red[6] + red[7];
    float mu   = sum * (1.f / D_MODEL);
    float var  = sq * (1.f / D_MODEL) - mu * mu;
    float rstd = rsqrtf(var + LN_EPS);
    int c = t * 4;
    float4 sv = *(const float4*)(sc + c);
    float4 bv = *(const float4*)(bi + c);
    float y0 = sv.x * (v0 - mu) * rstd + bv.x;
    float y1 = sv.y * (v1 - mu) * rstd + bv.y;
    float y2 = sv.z * (v2 - mu) * rstd + bv.z;
    float y3 = sv.w * (v3 - mu) * rstd + bv.w;
    unsigned long long pk = (unsigned long long)f2bf(y0)
        | ((unsigned long long)f2bf(y1) << 16)
        | ((unsigned long long)f2bf(y2) << 32)
        | ((unsigned long long)f2bf(y3) << 48);
    *(unsigned long long*)(xb + base) = pk;
}

// ------- ln5: residual(xb + 4 partials) + LayerNorm (for split-K=4 FFN2) -------
__global__ __launch_bounds__(256) void ln5(
    unsigned short* __restrict__ xb, const unsigned short* __restrict__ p,
    const float* __restrict__ sc, const float* __restrict__ bi)
{
    const int row = blockIdx.x;
    const int t = threadIdx.x;
    const size_t base = (size_t)row * D_MODEL + t * 4;
    const size_t stride = (size_t)ROWS * D_MODEL;
    ushort4 xu = *(const ushort4*)(xb + base);
    float v0 = bf2f(xu.x), v1 = bf2f(xu.y), v2 = bf2f(xu.z), v3 = bf2f(xu.w);
#pragma unroll
    for (int k = 0; k < 4; k++) {
        ushort4 pu = *(const ushort4*)(p + k * stride + base);
        v0 += bf2f(pu.x); v1 += bf2f(pu.y); v2 += bf2f(pu.z); v3 += bf2f(pu.w);
    }
    float sum = v0 + v1 + v2 + v3;
    float sq  = v0 * v0 + v1 * v1 + v2 * v2 + v3 * v3;
#pragma unroll
    for (int off = 1; off < 64; off <<= 1) {
        sum += __shfl_xor(sum, off);
        sq  += __shfl_xor(sq, off);
    }
    __shared__ float red[8];
    int wid = t >> 6, lane = t & 63;
    if (lane == 0) { red[wid] = sum; red[4 + wid] = sq; }
    __syncthreads();
    sum = red[0] + red[1] + red[2] + red[3];
    sq  = red[4] + red[5] + red[6] + red[7];
    float mu   = sum * (1.f / D_MODEL);
    float var  = sq * (1.f / D_MODEL) - mu * mu;
    float rstd = rsqrtf(var + LN_EPS);
    int c = t * 4;
    float4 sv = *(const float4*)(sc + c);
    float4 bv = *(const float4*)(bi + c);
    float y0 = sv.x * (v0 - mu) * rstd + bv.x;
    float y1 = sv.y * (v1 - mu) * rstd + bv.y;
    float y2 = sv.z * (v2 - mu) * rstd + bv.z;
    float y3 = sv.w * (v3 - mu) * rstd + bv.w;
    unsigned long long pk = (unsigned long long)f2bf(y0)
        | ((unsigned long long)f2bf(y1) << 16)
        | ((unsigned long long)f2bf(y2) << 32)
        | ((unsigned long long)f2bf(y3) << 48);
    *(unsigned long long*)(xb + base) = pk;
}

// ---------------- launcher ----------------
extern "C" void kernel_launch(void* const* d_in, const int* in_sizes, int n_in,
                              void* d_out, int out_size, void* d_ws, size_t ws_size,
                              hipStream_t stream)
{
    (void)in_sizes; (void)n_in; (void)out_size;
    const int*   tokens = (const int*)d_in[0];
    const float* emb  = (const float*)d_in[2];
    const float* pose = (const float*)d_in[3];
    const float* Wq = (const float*)d_in[4];
    const float* bq = (const float*)d_in[5];
    const float* Wk = (const float*)d_in[6];
    const float* bk = (const float*)d_in[7];
    const float* Wv = (const float*)d_in[8];
    const float* bv = (const float*)d_in[9];
    const float* Wo = (const float*)d_in[10];
    const float* bo = (const float*)d_in[11];
    const float* n1s = (const float*)d_in[12];
    const float* n1b = (const float*)d_in[13];
    const float* W1 = (const float*)d_in[14];
    const float* b1 = (const float*)d_in[15];
    const float* W2 = (const float*)d_in[16];
    const float* b2 = (const float*)d_in[17];
    const float* n2s = (const float*)d_in[18];
    const float* n2b = (const float*)d_in[19];

    char* w = (char*)d_ws;
    size_t off = 0;
    auto carve = [&](size_t bytes) -> void* {
        void* p = w + off;
        off = (off + bytes + 255) & ~(size_t)255;
        return p;
    };
    unsigned short* tmp = (unsigned short*)carve((size_t)4 * ROWS * D_MODEL * 2);  // 4 bf16 partials
    unsigned short* xb    = (unsigned short*)carve((size_t)ROWS * D_MODEL * 2);   // bf16 residual
    unsigned short* qkvb  = (unsigned short*)carve((size_t)ROWS * QKV_N * 2);
    unsigned short* cbuf  = (unsigned short*)carve((size_t)ROWS * D_MODEL * 2);
    unsigned short* hbuf  = (unsigned short*)carve((size_t)ROWS * FF_DIM * 2);
    unsigned short* wt = (unsigned short*)carve((size_t)12 * 1048576 * 2);  // per-layer fused (24MB)
    float* bqkv = (float*)carve((size_t)NLAYER * QKV_N * 4);
    unsigned short* embb = qkvb;   // tied-head emb aliases dead qkv/ctx/h region
    unsigned short* tmp1 = tmp + (size_t)ROWS * D_MODEL;
    if (off > ws_size) return;

    bias3_k<<<NLAYER * 3, 256, 0, stream>>>(bq, bk, bv, bqkv);
    embed_k<<<ROWS, 256, 0, stream>>>(tokens, emb, pose, xb);

    for (int l = 0; l < NLAYER; l++) {
        unsigned short* wtQKV = wt;
        unsigned short* wtWo  = wt + (size_t)3 * 1048576;
        unsigned short* wtW1  = wt + (size_t)4 * 1048576;
        unsigned short* wtW2  = wt + (size_t)8 * 1048576;

        transpose_all<<<3072, 256, 0, stream>>>(
            Wq + (size_t)l * D_MODEL * D_MODEL, Wk + (size_t)l * D_MODEL * D_MODEL,
            Wv + (size_t)l * D_MODEL * D_MODEL, Wo + (size_t)l * D_MODEL * D_MODEL,
            W1 + (size_t)l * D_MODEL * FF_DIM,  W2 + (size_t)l * FF_DIM * D_MODEL, wt);

        // QKV: gemm256 (192 blocks, one round) — isolated switch this round
        gemm256<1, 1><<<dim3((QKV_N / 256) * 16, 1), 512, 0, stream>>>(
            xb, D_MODEL, wtQKV, D_MODEL, bqkv + (size_t)l * QKV_N, qkvb, QKV_N, D_MODEL);

        attn_fwd<<<dim3(8, BATCH * NHEAD), 256, 0, stream>>>(qkvb, cbuf);

        gemm_bt<1><<<dim3(256, 2), 256, 0, stream>>>(cbuf, D_MODEL, wtWo, D_MODEL,
                                                     bo + (size_t)l * D_MODEL, tmp, D_MODEL, D_MODEL / 2);
        ln3<<<ROWS, 256, 0, stream>>>(xb, tmp, tmp1, n1s + (size_t)l * D_MODEL, n1b + (size_t)l * D_MODEL);

        gemm256<2, 1><<<dim3((FF_DIM / 256) * 16, 1), 512, 0, stream>>>(
            xb, D_MODEL, wtW1, D_MODEL, b1 + (size_t)l * FF_DIM, hbuf, FF_DIM, D_MODEL);
        // FFN2: gemm256 split-K=4 -> 64 x 4 = 256 blocks (one full round)
        gemm256<1, 1><<<dim3((D_MODEL / 256) * 16, 4), 512, 0, stream>>>(
            hbuf, FF_DIM, wtW2, FF_DIM, b2 + (size_t)l * D_MODEL, tmp, D_MODEL, FF_DIM / 4);
        ln5<<<ROWS, 256, 0, stream>>>(xb, tmp, n2s + (size_t)l * D_MODEL, n2b + (size_t)l * D_MODEL);
    }

    cast_bf<<<(VOCAB * D_MODEL) / 1024, 256, 0, stream>>>(emb, embb, (size_t)VOCAB * D_MODEL);
    // head: NO XCD swizzle — bm-fastest order shares B panels via L3
    gemm256<0, 0><<<dim3((VOCAB / 256) * 16, 1), 512, 0, stream>>>(
        xb, D_MODEL, embb, D_MODEL, nullptr, d_out, VOCAB, D_MODEL);
}

// Round 16
// 1888.158 us; speedup vs baseline: 1.1269x; 1.0372x over previous
//
#include <hip/hip_runtime.h>

#define D_MODEL 1024
#define SEQ     1024
#define BATCH   4
#define NHEAD   16
#define HDIM    64
#define FF_DIM  4096
#define NLAYER  8
#define VOCAB   32000
#define ROWS    (BATCH*SEQ)
#define QKV_N   3072
#define LN_EPS  1e-5f

typedef __attribute__((ext_vector_type(4))) float   f32x4;
typedef __attribute__((ext_vector_type(8))) unsigned short u16x8;
typedef __attribute__((ext_vector_type(8))) __bf16  bf16x8;

typedef const unsigned int __attribute__((address_space(1)))* gas_t;
typedef unsigned int __attribute__((address_space(3)))* las_t;

__device__ __forceinline__ void gld16(const void* g, void* l) {
    __builtin_amdgcn_global_load_lds((gas_t)g, (las_t)l, 16, 0, 0);
}

__device__ __forceinline__ unsigned short f2bf(float f) {
    unsigned int u = __builtin_bit_cast(unsigned int, f);
    u += 0x7FFFu + ((u >> 16) & 1u);   // RNE
    return (unsigned short)(u >> 16);
}

__device__ __forceinline__ float bf2f(unsigned short u) {
    return __builtin_bit_cast(float, (unsigned int)u << 16);
}

__device__ __forceinline__ f32x4 mfma32(u16x8 a, u16x8 b, f32x4 c) {
    return __builtin_amdgcn_mfma_f32_16x16x32_bf16(
        __builtin_bit_cast(bf16x8, a), __builtin_bit_cast(bf16x8, b), c, 0, 0, 0);
}

// ---------------- embed: xb = bf16(emb[tok] + pos) ----------------
__global__ __launch_bounds__(256) void embed_k(
    const int* __restrict__ tok, const float* __restrict__ emb,
    const float* __restrict__ pos, unsigned short* __restrict__ xb)
{
    int bs = blockIdx.x;
    int s  = bs & (SEQ - 1);
    int tk = tok[bs];
    int c  = threadIdx.x * 4;
    float4 e = *(const float4*)(emb + (size_t)tk * D_MODEL + c);
    float4 p = *(const float4*)(pos + (size_t)s * D_MODEL + c);
    float y0 = e.x + p.x, y1 = e.y + p.y, y2 = e.z + p.z, y3 = e.w + p.w;
    size_t base = (size_t)bs * D_MODEL + c;
    unsigned long long pk = (unsigned long long)f2bf(y0)
        | ((unsigned long long)f2bf(y1) << 16)
        | ((unsigned long long)f2bf(y2) << 32)
        | ((unsigned long long)f2bf(y3) << 48);
    *(unsigned long long*)(xb + base) = pk;
}

// ---------------- cast fp32 -> bf16 ----------------
__global__ __launch_bounds__(256) void cast_bf(
    const float* __restrict__ in, unsigned short* __restrict__ out, size_t n)
{
    size_t i = ((size_t)blockIdx.x * 256 + threadIdx.x) * 4;
    if (i >= n) return;
    float4 v = *(const float4*)(in + i);
    unsigned long long pk = (unsigned long long)f2bf(v.x)
        | ((unsigned long long)f2bf(v.y) << 16)
        | ((unsigned long long)f2bf(v.z) << 32)
        | ((unsigned long long)f2bf(v.w) << 48);
    *(unsigned long long*)(out + i) = pk;
}

// ---------------- concat qkv biases ----------------
__global__ __launch_bounds__(256) void bias3_k(
    const float* __restrict__ bq, const float* __restrict__ bk,
    const float* __restrict__ bv, float* __restrict__ out)
{
    int l = blockIdx.x / 3, which = blockIdx.x % 3;
    const float* src = which == 0 ? bq : (which == 1 ? bk : bv);
    int i = threadIdx.x * 4;
    float4 v = *(const float4*)(src + (size_t)l * D_MODEL + i);
    *(float4*)(out + (size_t)l * QKV_N + which * D_MODEL + i) = v;
}

// ---------------- transpose tile body (shared) ----------------
__device__ __forceinline__ void tc_tile(
    const float* __restrict__ W, unsigned short* __restrict__ Wt,
    int K, int N, int n0, int k0)
{
    __shared__ float t[64][65];
    int rr = threadIdx.x >> 4;          // 0..15
    int cc = (threadIdx.x & 15) * 4;    // 0..60
#pragma unroll
    for (int it = 0; it < 4; it++) {
        int r = it * 16 + rr;
        float4 v = *(const float4*)(W + (size_t)(k0 + r) * N + n0 + cc);
        t[r][cc] = v.x; t[r][cc + 1] = v.y; t[r][cc + 2] = v.z; t[r][cc + 3] = v.w;
    }
    __syncthreads();
#pragma unroll
    for (int it = 0; it < 4; it++) {
        int n = it * 16 + rr;
        unsigned long long pk = (unsigned long long)f2bf(t[cc][n])
            | ((unsigned long long)f2bf(t[cc + 1][n]) << 16)
            | ((unsigned long long)f2bf(t[cc + 2][n]) << 32)
            | ((unsigned long long)f2bf(t[cc + 3][n]) << 48);
        *(unsigned long long*)(Wt + (size_t)(n0 + n) * K + k0 + cc) = pk;
    }
}

// ---------------- per-layer fused transpose: Wq,Wk,Wv,Wo,W1,W2 in ONE launch ----
// wt layout (elems): [0,3M) qkv^T, [3M,4M) Wo^T, [4M,8M) W1^T, [8M,12M) W2^T
__global__ __launch_bounds__(256) void transpose_all(
    const float* __restrict__ Wq, const float* __restrict__ Wk,
    const float* __restrict__ Wv, const float* __restrict__ Wo,
    const float* __restrict__ W1, const float* __restrict__ W2,
    unsigned short* __restrict__ wt)
{
    int b = blockIdx.x;
    const float* W; unsigned short* out; int K, N, t;
    if (b < 768)       { int w = b >> 8; t = b & 255; W = w == 0 ? Wq : (w == 1 ? Wk : Wv);
                         out = wt + (size_t)w * 1048576; K = 1024; N = 1024; }
    else if (b < 1024) { t = b - 768;  W = Wo; out = wt + (size_t)3 * 1048576; K = 1024; N = 1024; }
    else if (b < 2048) { t = b - 1024; W = W1; out = wt + (size_t)4 * 1048576; K = 1024; N = 4096; }
    else               { t = b - 2048; W = W2; out = wt + (size_t)8 * 1048576; K = 4096; N = 1024; }
    int ntx = N >> 6;
    tc_tile(W, out, K, N, (t % ntx) * 64, (t / ntx) * 64);
}

// ---------------- small NT GEMM (m97 128x128) with split-K support ----------------
// MODE 1: bf16 out; MODE 2: relu->bf16 out.
template<int MODE>
__global__ __launch_bounds__(256, 3) void gemm_bt(
    const unsigned short* __restrict__ A, int lda,
    const unsigned short* __restrict__ Bt, int ldb,
    const float* __restrict__ bias, void* __restrict__ Cout, int N, int Klen)
{
    __shared__ unsigned short As[128 * 32];
    __shared__ unsigned short Bs[128 * 32];
    const int part = blockIdx.y;
    A  += (size_t)part * Klen;
    Bt += (size_t)part * Klen;
    int flat = blockIdx.x;
    const int bm = flat & 31, bn = flat >> 5;
    const int tid  = threadIdx.x;
    const int wid  = tid >> 6, lane = tid & 63;
    const int l16  = lane & 15, lhi = lane >> 4;
    const int wr   = wid >> 1, wc = wid & 1;

    const int srow = wid * 32 + (lane >> 2);
    const int scol = (lane & 3) * 8;
    const unsigned short* gA0 = A  + ((size_t)bm * 128 + srow) * lda + scol;
    const unsigned short* gB0 = Bt + ((size_t)bn * 128 + srow) * ldb + scol;
    unsigned short* lA = As + wid * 32 * 32;
    unsigned short* lB = Bs + wid * 32 * 32;

    f32x4 acc[4][4];
#pragma unroll
    for (int i = 0; i < 4; i++)
#pragma unroll
        for (int j = 0; j < 4; j++) acc[i][j] = (f32x4){0.f, 0.f, 0.f, 0.f};

    for (int k0 = 0; k0 < Klen; k0 += 32) {
        __syncthreads();
        gld16(gA0 + k0,                    lA);
        gld16(gA0 + k0 + 16 * (size_t)lda, lA + 16 * 32);
        gld16(gB0 + k0,                    lB);
        gld16(gB0 + k0 + 16 * (size_t)ldb, lB + 16 * 32);
        __syncthreads();
        u16x8 af[4], bfr[4];
#pragma unroll
        for (int i = 0; i < 4; i++)
            af[i] = *(const u16x8*)(As + (wr * 64 + i * 16 + l16) * 32 + lhi * 8);
#pragma unroll
        for (int i = 0; i < 4; i++)
            bfr[i] = *(const u16x8*)(Bs + (wc * 64 + i * 16 + l16) * 32 + lhi * 8);
#pragma unroll
        for (int mi = 0; mi < 4; mi++)
#pragma unroll
            for (int ni = 0; ni < 4; ni++)
                acc[mi][ni] = mfma32(af[mi], bfr[ni], acc[mi][ni]);
    }

    const size_t pofs = (size_t)part * (size_t)ROWS * N;
    // epilogue: j-then-ni order so 4 stores cover 128B contiguous per row
#pragma unroll
    for (int mi = 0; mi < 4; mi++) {
        float bv[4];
#pragma unroll
        for (int ni = 0; ni < 4; ni++)
            bv[ni] = (bias && part == 0) ? bias[bn * 128 + wc * 64 + ni * 16 + l16] : 0.f;
#pragma unroll
        for (int j = 0; j < 4; j++) {
            int row = bm * 128 + wr * 64 + mi * 16 + lhi * 4 + j;
#pragma unroll
            for (int ni = 0; ni < 4; ni++) {
                int col = bn * 128 + wc * 64 + ni * 16 + l16;
                float v = acc[mi][ni][j] + bv[ni];
                size_t idx = pofs + (size_t)row * N + col;
                if constexpr (MODE == 1) {
                    ((unsigned short*)Cout)[idx] = f2bf(v);
                } else {
                    ((unsigned short*)Cout)[idx] = f2bf(v > 0.f ? v : 0.f);
                }
            }
        }
    }
}

// ====== 256x256 8-phase GEMM (R4-best structure + NT store), split-K capable ======
#define PSYNC() do { __builtin_amdgcn_s_barrier(); \
    asm volatile("s_waitcnt lgkmcnt(0)" ::: "memory"); \
    __builtin_amdgcn_sched_barrier(0); } while (0)
#define PEND() __builtin_amdgcn_s_barrier()
#define VM4()  asm volatile("s_waitcnt vmcnt(4)" ::: "memory")

#define LOADA(reg, half) do { \
    _Pragma("unroll") \
    for (int m_ = 0; m_ < 4; m_++) { \
        aF[m_][0] = *(const u16x8*)((reg) + ((half)*4 + m_) * 2048 + lane0); \
        aF[m_][1] = *(const u16x8*)((reg) + ((half)*4 + m_) * 2048 + lane1); \
    } } while (0)

#define LOADB(reg, np) do { \
    _Pragma("unroll") \
    for (int n_ = 0; n_ < 2; n_++) { \
        bF[(np)*2 + n_][0] = *(const u16x8*)((reg) + ((np)*2 + n_) * 2048 + lane0); \
        bF[(np)*2 + n_][1] = *(const u16x8*)((reg) + ((np)*2 + n_) * 2048 + lane1); \
    } } while (0)

#define MFMA8(ma, np) do { \
    __builtin_amdgcn_s_setprio(1); \
    _Pragma("unroll") \
    for (int m_ = 0; m_ < 4; m_++) \
        _Pragma("unroll") \
        for (int n_ = 0; n_ < 2; n_++) { \
            acc[(ma)+m_][(np)*2+n_] = mfma32(aF[m_][0], bF[(np)*2+n_][0], acc[(ma)+m_][(np)*2+n_]); \
            acc[(ma)+m_][(np)*2+n_] = mfma32(aF[m_][1], bF[(np)*2+n_][1], acc[(ma)+m_][(np)*2+n_]); \
        } \
    __builtin_amdgcn_s_setprio(0); \
} while (0)

template<int MODE, int SWZ>
__global__ __launch_bounds__(512, 2) void gemm256(
    const unsigned short* __restrict__ A, int lda,
    const unsigned short* __restrict__ Bt, int ldb,
    const float* __restrict__ bias, void* __restrict__ Cout, int N, int Klen)
{
    __shared__ unsigned short lds[65536] __attribute__((aligned(128)));
    const int tid = threadIdx.x, wid = tid >> 6, lane = tid & 63;
    const int l16 = lane & 15, lhi = lane >> 4;
    const int wr = wid >> 2, wc = wid & 3;

    const int part = blockIdx.y;
    A  += (size_t)part * Klen;
    Bt += (size_t)part * Klen;

    int flat = blockIdx.x;
    if constexpr (SWZ) {
        int cpx = gridDim.x >> 3; flat = (flat & 7) * cpx + (flat >> 3);
    }
    const int bm = flat & 15, bn = flat >> 4;
    const int NT = Klen >> 6;

    const int srowL = tid >> 3;                                      // 0..63
    const int scolb = ((tid & 7) << 4) ^ (((tid >> 3) & 7) << 4);    // bytes (pre-swz src)
    const unsigned short* baseA = A  + (size_t)(bm * 256 + srowL) * lda + (scolb >> 1);
    const unsigned short* baseB = Bt + (size_t)(bn * 256 + srowL) * ldb + (scolb >> 1);
    unsigned short* dst0 = lds + wid * 512;   // wave-uniform; HW adds lane*16B

    auto stage = [&](int isB, int tile, int h) {   // one half-tile = 2 gld16
        const size_t ld = isB ? (size_t)ldb : (size_t)lda;
        const unsigned short* s = (isB ? baseB : baseA) + (size_t)(h * 128) * ld + (size_t)tile * 64;
        unsigned short* d = dst0 + (tile & 1) * 32768 + isB * 16384 + h * 8192;
        gld16(s, d);
        gld16(s + 64 * ld, d + 4096);
    };

    const int lswz  = (l16 & 7) << 4;
    const int lane0 = ((lhi * 16) ^ lswz) + l16 * 128;
    const int lane1 = ((64 + lhi * 16) ^ lswz) + l16 * 128;

    const char* aR0 = (const char*)lds + wr * 16384;
    const char* bR0 = (const char*)lds + 32768 + (wc >> 1) * 16384 + (wc & 1) * 8192;
    const char* aR1 = aR0 + 65536;
    const char* bR1 = bR0 + 65536;

    f32x4 acc[8][4];
#pragma unroll
    for (int i = 0; i < 8; i++)
#pragma unroll
        for (int j = 0; j < 4; j++) acc[i][j] = (f32x4){0.f, 0.f, 0.f, 0.f};
    u16x8 aF[4][2], bF[4][2];

    // prologue: B(0),A(0),B(1); leave B(1)'s 4 loads in flight
    stage(1, 0, 0); stage(1, 0, 1);
    stage(0, 0, 0); stage(0, 0, 1);
    stage(1, 1, 0); stage(1, 1, 1);
    VM4();
    __builtin_amdgcn_s_barrier();

    for (int t = 0; t < NT; t += 2) {
        const bool more = (t + 2) < NT;
        // ---- K-tile t (buf0) ----
        LOADA(aR0, 0); LOADB(bR0, 0); stage(0, t + 1, 0);
        PSYNC(); MFMA8(0, 0); PEND();
        LOADB(bR0, 1);                stage(0, t + 1, 1);
        PSYNC(); MFMA8(0, 1); PEND();
        LOADA(aR0, 1);                if (more) stage(1, t + 2, 0);
        PSYNC(); MFMA8(4, 0); PEND();
        if (more) { stage(1, t + 2, 1); VM4(); }
        else      { asm volatile("s_waitcnt vmcnt(0)" ::: "memory"); }
        PSYNC(); MFMA8(4, 1); PEND();
        // ---- K-tile t+1 (buf1) ----
        LOADA(aR1, 0); LOADB(bR1, 0); if (more) stage(0, t + 2, 0);
        PSYNC(); MFMA8(0, 0); PEND();
        LOADB(bR1, 1);                if (more) stage(0, t + 2, 1);
        PSYNC(); MFMA8(0, 1); PEND();
        LOADA(aR1, 1);                if (more) stage(1, t + 3, 0);
        PSYNC(); MFMA8(4, 0); PEND();
        if (more) { stage(1, t + 3, 1); VM4(); }
        PSYNC(); MFMA8(4, 1); PEND();
    }

    const size_t pofs = (size_t)part * (size_t)ROWS * N;
    // epilogue: j-then-ni order -> 4 consecutive stores cover one full line
#pragma unroll
    for (int mi = 0; mi < 8; mi++) {
        float bv[4];
#pragma unroll
        for (int ni = 0; ni < 4; ni++)
            bv[ni] = (bias && part == 0) ? bias[bn * 256 + wc * 64 + ni * 16 + l16] : 0.f;
#pragma unroll
        for (int j = 0; j < 4; j++) {
            int row = bm * 256 + wr * 128 + mi * 16 + lhi * 4 + j;
#pragma unroll
            for (int ni = 0; ni < 4; ni++) {
                int col = bn * 256 + wc * 64 + ni * 16 + l16;
                float v = acc[mi][ni][j] + bv[ni];
                size_t idx = pofs + (size_t)row * N + col;
                if constexpr (MODE == 0) {
                    __builtin_nontemporal_store(v, (float*)Cout + idx);
                } else if constexpr (MODE == 1) {
                    ((unsigned short*)Cout)[idx] = f2bf(v);
                } else {
                    ((unsigned short*)Cout)[idx] = f2bf(v > 0.f ? v : 0.f);
                }
            }
        }
    }
}

// ------- flash attention (causal), paired q-tiles + T14 async double-buffered staging -------
__global__ __launch_bounds__(256, 3) void attn_fwd(
    const unsigned short* __restrict__ qkv, unsigned short* __restrict__ ctxb)
{
    __shared__ unsigned short Ks[2][64 * 72];
    __shared__ unsigned short Vs[2][64 * 72];   // transposed: Vs[d][kv]
    __shared__ unsigned short Ps[4 * 16 * 72];
    const int tid = threadIdx.x;
    const int wid = tid >> 6, lane = tid & 63;
    const int l16 = lane & 15, lhi = lane >> 4;
    const int bh  = blockIdx.y, b = bh >> 4, h = bh & 15;
    const int p   = blockIdx.x;          // 0..7
    const int qA0 = p * 64;
    const int qB0 = (15 - p) * 64;
    const size_t rowbase = (size_t)b * SEQ;

    const unsigned short* qpA = qkv + (rowbase + qA0 + wid * 16 + l16) * QKV_N + h * HDIM + lhi * 8;
    u16x8 qAf0 = *(const u16x8*)qpA;
    u16x8 qAf1 = *(const u16x8*)(qpA + 32);
    const unsigned short* qpB = qkv + (rowbase + qB0 + wid * 16 + l16) * QKV_N + h * HDIM + lhi * 8;
    u16x8 qBf0 = *(const u16x8*)qpB;
    u16x8 qBf1 = *(const u16x8*)(qpB + 32);

    f32x4 oaA[4], oaB[4];
    float mjA[4], ljA[4], mjB[4], ljB[4];
#pragma unroll
    for (int i = 0; i < 4; i++) {
        oaA[i] = (f32x4){0.f, 0.f, 0.f, 0.f};
        oaB[i] = (f32x4){0.f, 0.f, 0.f, 0.f};
        mjA[i] = -1e30f; ljA[i] = 0.f;
        mjB[i] = -1e30f; ljB[i] = 0.f;
    }

    // staging thread addresses
    const int kr0r = tid >> 3,         kr0d = (tid & 7) * 8;          // K elem 0
    const int kr1r = (256 + tid) >> 3, kr1d = (tid & 7) * 8;          // K elem 1
    const int vr0  = (tid & 15) * 4,   vd0  = (tid >> 4) * 8;         // V (tid<128)
    u16x8 kp0, kp1, vp0, vp1, vp2, vp3;   // prefetch regs

    auto ldKV = [&](int kv0) {
        kp0 = *(const u16x8*)(qkv + (rowbase + kv0 + kr0r) * QKV_N + D_MODEL + h * HDIM + kr0d);
        kp1 = *(const u16x8*)(qkv + (rowbase + kv0 + kr1r) * QKV_N + D_MODEL + h * HDIM + kr1d);
        if (tid < 128) {
            const unsigned short* vp = qkv + (rowbase + kv0 + vr0) * QKV_N
                                       + 2 * D_MODEL + h * HDIM + vd0;
            vp0 = *(const u16x8*)vp;
            vp1 = *(const u16x8*)(vp + QKV_N);
            vp2 = *(const u16x8*)(vp + 2 * QKV_N);
            vp3 = *(const u16x8*)(vp + 3 * QKV_N);
        }
    };
    auto wrKV = [&](int buf) {
        *(u16x8*)(&Ks[buf][kr0r * 72 + kr0d]) = kp0;
        *(u16x8*)(&Ks[buf][kr1r * 72 + kr1d]) = kp1;
        if (tid < 128) {
#pragma unroll
            for (int j = 0; j < 8; j++) {
                unsigned long long pk = (unsigned long long)vp0[j]
                    | ((unsigned long long)vp1[j] << 16)
                    | ((unsigned long long)vp2[j] << 32)
                    | ((unsigned long long)vp3[j] << 48);
                *(unsigned long long*)(&Vs[buf][(vd0 + j) * 72 + vr0]) = pk;
            }
        }
    };

    auto update = [&](u16x8 qf0, u16x8 qf1, f32x4 (&oa)[4],
                      float (&mj)[4], float (&lj)[4], int q0, int kv0, int buf) {
        f32x4 sa[4];
        __builtin_amdgcn_s_setprio(1);
#pragma unroll
        for (int ni = 0; ni < 4; ni++) {
            f32x4 z = (f32x4){0.f, 0.f, 0.f, 0.f};
            u16x8 k0f = *(const u16x8*)(&Ks[buf][(ni * 16 + l16) * 72 + lhi * 8]);
            u16x8 k1f = *(const u16x8*)(&Ks[buf][(ni * 16 + l16) * 72 + 32 + lhi * 8]);
            z = mfma32(qf0, k0f, z);
            z = mfma32(qf1, k1f, z);
            sa[ni] = z;
        }
        __builtin_amdgcn_s_setprio(0);
        float tm[4] = {-1e30f, -1e30f, -1e30f, -1e30f};
#pragma unroll
        for (int ni = 0; ni < 4; ni++)
#pragma unroll
            for (int j = 0; j < 4; j++) {
                float v = sa[ni][j] * 0.125f;
                int row = q0 + wid * 16 + lhi * 4 + j;
                int col = kv0 + ni * 16 + l16;
                if (col > row) v = -1e30f;
                sa[ni][j] = v;
                tm[j] = fmaxf(tm[j], v);
            }
#pragma unroll
        for (int j = 0; j < 4; j++) {
#pragma unroll
            for (int off = 1; off < 16; off <<= 1)
                tm[j] = fmaxf(tm[j], __shfl_xor(tm[j], off));
        }
        float al[4], rs[4] = {0.f, 0.f, 0.f, 0.f};
#pragma unroll
        for (int j = 0; j < 4; j++) {
            float mn = fmaxf(mj[j], tm[j]);
            al[j] = __expf(mj[j] - mn);
            mj[j] = mn;
        }
#pragma unroll
        for (int ni = 0; ni < 4; ni++)
#pragma unroll
            for (int j = 0; j < 4; j++) {
                float pv = __expf(sa[ni][j] - mj[j]);
                rs[j] += pv;
                Ps[wid * 1152 + (lhi * 4 + j) * 72 + ni * 16 + l16] = f2bf(pv);
            }
#pragma unroll
        for (int j = 0; j < 4; j++) {
#pragma unroll
            for (int off = 1; off < 16; off <<= 1)
                rs[j] += __shfl_xor(rs[j], off);
            lj[j] = lj[j] * al[j] + rs[j];
        }
#pragma unroll
        for (int di = 0; di < 4; di++)
#pragma unroll
            for (int j = 0; j < 4; j++) oa[di][j] *= al[j];
        __builtin_amdgcn_s_setprio(1);
#pragma unroll
        for (int di = 0; di < 4; di++) {
#pragma unroll
            for (int kc = 0; kc < 2; kc++) {
                u16x8 pf = *(const u16x8*)(&Ps[wid * 1152 + l16 * 72 + kc * 32 + lhi * 8]);
                u16x8 vf = *(const u16x8*)(&Vs[buf][(di * 16 + l16) * 72 + kc * 32 + lhi * 8]);
                oa[di] = mfma32(pf, vf, oa[di]);
            }
        }
        __builtin_amdgcn_s_setprio(0);
    };

    const int ntB = 16 - p;   // kv tiles 0..15-p (covers both q-tiles)
    // prologue: stage tile 0 into buf 0
    ldKV(0);
    wrKV(0);
    __syncthreads();
    for (int kt = 0; kt < ntB; ++kt) {
        const int buf = kt & 1;
        const int kv0 = kt * 64;
        if (kt + 1 < ntB) ldKV(kv0 + 64);              // issue next-tile loads early
        if (kt <= p) update(qAf0, qAf1, oaA, mjA, ljA, qA0, kv0, buf);  // block-uniform
        update(qBf0, qBf1, oaB, mjB, ljB, qB0, kv0, buf);
        if (kt + 1 < ntB) wrKV(buf ^ 1);               // waits on its own loads (vmcnt)
        __syncthreads();                               // writes visible; WAR safe (see R16 notes)
    }

#pragma unroll
    for (int di = 0; di < 4; di++)
#pragma unroll
        for (int j = 0; j < 4; j++) {
            int rowA = qA0 + wid * 16 + lhi * 4 + j;
            ctxb[(rowbase + rowA) * D_MODEL + h * HDIM + di * 16 + l16] =
                f2bf(oaA[di][j] / ljA[j]);
            int rowB = qB0 + wid * 16 + lhi * 4 + j;
            ctxb[(rowbase + rowB) * D_MODEL + h * HDIM + di * 16 + l16] =
                f2bf(oaB[di][j] / ljB[j]);
        }
}

// ------- fused residual(xb + p0 + p1) + LayerNorm, bf16 in-place residual -------
__global__ __launch_bounds__(256) void ln3(
    unsigned short* __restrict__ xb, const unsigned short* __restrict__ p0,
    const unsigned short* __restrict__ p1,
    const float* __restrict__ sc, const float* __restrict__ bi)
{
    const int row = blockIdx.x;
    const int t = threadIdx.x;
    const size_t base = (size_t)row * D_MODEL + t * 4;
    ushort4 xu = *(const ushort4*)(xb + base);
    ushort4 au = *(const ushort4*)(p0 + base);
    ushort4 bu = *(const ushort4*)(p1 + base);
    float v0 = bf2f(xu.x) + bf2f(au.x) + bf2f(bu.x);
    float v1 = bf2f(xu.y) + bf2f(au.y) + bf2f(bu.y);
    float v2 = bf2f(xu.z) + bf2f(au.z) + bf2f(bu.z);
    float v3 = bf2f(xu.w) + bf2f(au.w) + bf2f(bu.w);
    float sum = v0 + v1 + v2 + v3;
    float sq  = v0 * v0 + v1 * v1 + v2 * v2 + v3 * v3;
#pragma unroll
    for (int off = 1; off < 64; off <<= 1) {
        sum += __shfl_xor(sum, off);
        sq  += __shfl_xor(sq, off);
    }
    __shared__ float red[8];
    int wid = t >> 6, lane = t & 63;
    if (lane == 0) { red[wid] = sum; red[4 + wid] = sq; }
    __syncthreads();
    sum = red[0] + red[1] + red[2] + red[3];
    sq  = red[4] + red[5] + red[6] + red[7];
    float mu   = sum * (1.f / D_MODEL);
    float var  = sq * (1.f / D_MODEL) - mu * mu;
    float rstd = rsqrtf(var + LN_EPS);
    int c = t * 4;
    float4 sv = *(const float4*)(sc + c);
    float4 bv = *(const float4*)(bi + c);
    float y0 = sv.x * (v0 - mu) * rstd + bv.x;
    float y1 = sv.y * (v1 - mu) * rstd + bv.y;
    float y2 = sv.z * (v2 - mu) * rstd + bv.z;
    float y3 = sv.w * (v3 - mu) * rstd + bv.w;
    unsigned long long pk = (unsigned long long)f2bf(y0)
        | ((unsigned long long)f2bf(y1) << 16)
        | ((unsigned long long)f2bf(y2) << 32)
        | ((unsigned long long)f2bf(y3) << 48);
    *(unsigned long long*)(xb + base) = pk;
}

// ------- ln5: residual(xb + 4 partials) + LayerNorm (for split-K=4 FFN2) -------
__global__ __launch_bounds__(256) void ln5(
    unsigned short* __restrict__ xb, const unsigned short* __restrict__ p,
    const float* __restrict__ sc, const float* __restrict__ bi)
{
    const int row = blockIdx.x;
    const int t = threadIdx.x;
    const size_t base = (size_t)row * D_MODEL + t * 4;
    const size_t stride = (size_t)ROWS * D_MODEL;
    ushort4 xu = *(const ushort4*)(xb + base);
    float v0 = bf2f(xu.x), v1 = bf2f(xu.y), v2 = bf2f(xu.z), v3 = bf2f(xu.w);
#pragma unroll
    for (int k = 0; k < 4; k++) {
        ushort4 pu = *(const ushort4*)(p + k * stride + base);
        v0 += bf2f(pu.x); v1 += bf2f(pu.y); v2 += bf2f(pu.z); v3 += bf2f(pu.w);
    }
    float sum = v0 + v1 + v2 + v3;
    float sq  = v0 * v0 + v1 * v1 + v2 * v2 + v3 * v3;
#pragma unroll
    for (int off = 1; off < 64; off <<= 1) {
        sum += __shfl_xor(sum, off);
        sq  += __shfl_xor(sq, off);
    }
    __shared__ float red[8];
    int wid = t >> 6, lane = t & 63;
    if (lane == 0) { red[wid] = sum; red[4 + wid] = sq; }
    __syncthreads();
    sum = red[0] + red[1] + red[2] + red[3];
    sq  = red[4] + red[5] + red[6] + red[7];
    float mu   = sum * (1.f / D_MODEL);
    float var  = sq * (1.f / D_MODEL) - mu * mu;
    float rstd = rsqrtf(var + LN_EPS);
    int c = t * 4;
    float4 sv = *(const float4*)(sc + c);
    float4 bv = *(const float4*)(bi + c);
    float y0 = sv.x * (v0 - mu) * rstd + bv.x;
    float y1 = sv.y * (v1 - mu) * rstd + bv.y;
    float y2 = sv.z * (v2 - mu) * rstd + bv.z;
    float y3 = sv.w * (v3 - mu) * rstd + bv.w;
    unsigned long long pk = (unsigned long long)f2bf(y0)
        | ((unsigned long long)f2bf(y1) << 16)
        | ((unsigned long long)f2bf(y2) << 32)
        | ((unsigned long long)f2bf(y3) << 48);
    *(unsigned long long*)(xb + base) = pk;
}

// ---------------- launcher ----------------
extern "C" void kernel_launch(void* const* d_in, const int* in_sizes, int n_in,
                              void* d_out, int out_size, void* d_ws, size_t ws_size,
                              hipStream_t stream)
{
    (void)in_sizes; (void)n_in; (void)out_size;
    const int*   tokens = (const int*)d_in[0];
    const float* emb  = (const float*)d_in[2];
    const float* pose = (const float*)d_in[3];
    const float* Wq = (const float*)d_in[4];
    const float* bq = (const float*)d_in[5];
    const float* Wk = (const float*)d_in[6];
    const float* bk = (const float*)d_in[7];
    const float* Wv = (const float*)d_in[8];
    const float* bv = (const float*)d_in[9];
    const float* Wo = (const float*)d_in[10];
    const float* bo = (const float*)d_in[11];
    const float* n1s = (const float*)d_in[12];
    const float* n1b = (const float*)d_in[13];
    const float* W1 = (const float*)d_in[14];
    const float* b1 = (const float*)d_in[15];
    const float* W2 = (const float*)d_in[16];
    const float* b2 = (const float*)d_in[17];
    const float* n2s = (const float*)d_in[18];
    const float* n2b = (const float*)d_in[19];

    char* w = (char*)d_ws;
    size_t off = 0;
    auto carve = [&](size_t bytes) -> void* {
        void* p = w + off;
        off = (off + bytes + 255) & ~(size_t)255;
        return p;
    };
    unsigned short* tmp = (unsigned short*)carve((size_t)4 * ROWS * D_MODEL * 2);  // 4 bf16 partials
    unsigned short* xb    = (unsigned short*)carve((size_t)ROWS * D_MODEL * 2);   // bf16 residual
    unsigned short* qkvb  = (unsigned short*)carve((size_t)ROWS * QKV_N * 2);
    unsigned short* cbuf  = (unsigned short*)carve((size_t)ROWS * D_MODEL * 2);
    unsigned short* hbuf  = (unsigned short*)carve((size_t)ROWS * FF_DIM * 2);
    unsigned short* wt = (unsigned short*)carve((size_t)12 * 1048576 * 2);  // per-layer fused (24MB)
    float* bqkv = (float*)carve((size_t)NLAYER * QKV_N * 4);
    unsigned short* embb = qkvb;   // tied-head emb aliases dead qkv/ctx/h region
    unsigned short* tmp1 = tmp + (size_t)ROWS * D_MODEL;
    if (off > ws_size) return;

    bias3_k<<<NLAYER * 3, 256, 0, stream>>>(bq, bk, bv, bqkv);
    embed_k<<<ROWS, 256, 0, stream>>>(tokens, emb, pose, xb);

    for (int l = 0; l < NLAYER; l++) {
        unsigned short* wtQKV = wt;
        unsigned short* wtWo  = wt + (size_t)3 * 1048576;
        unsigned short* wtW1  = wt + (size_t)4 * 1048576;
        unsigned short* wtW2  = wt + (size_t)8 * 1048576;

        transpose_all<<<3072, 256, 0, stream>>>(
            Wq + (size_t)l * D_MODEL * D_MODEL, Wk + (size_t)l * D_MODEL * D_MODEL,
            Wv + (size_t)l * D_MODEL * D_MODEL, Wo + (size_t)l * D_MODEL * D_MODEL,
            W1 + (size_t)l * D_MODEL * FF_DIM,  W2 + (size_t)l * FF_DIM * D_MODEL, wt);

        gemm256<1, 1><<<dim3((QKV_N / 256) * 16, 1), 512, 0, stream>>>(
            xb, D_MODEL, wtQKV, D_MODEL, bqkv + (size_t)l * QKV_N, qkvb, QKV_N, D_MODEL);

        attn_fwd<<<dim3(8, BATCH * NHEAD), 256, 0, stream>>>(qkvb, cbuf);

        gemm_bt<1><<<dim3(256, 2), 256, 0, stream>>>(cbuf, D_MODEL, wtWo, D_MODEL,
                                                     bo + (size_t)l * D_MODEL, tmp, D_MODEL, D_MODEL / 2);
        ln3<<<ROWS, 256, 0, stream>>>(xb, tmp, tmp1, n1s + (size_t)l * D_MODEL, n1b + (size_t)l * D_MODEL);

        gemm256<2, 1><<<dim3((FF_DIM / 256) * 16, 1), 512, 0, stream>>>(
            xb, D_MODEL, wtW1, D_MODEL, b1 + (size_t)l * FF_DIM, hbuf, FF_DIM, D_MODEL);
        // FFN2: gemm256 split-K=4 -> 64 x 4 = 256 blocks (one full round)
        gemm256<1, 1><<<dim3((D_MODEL / 256) * 16, 4), 512, 0, stream>>>(
            hbuf, FF_DIM, wtW2, FF_DIM, b2 + (size_t)l * D_MODEL, tmp, D_MODEL, FF_DIM / 4);
        ln5<<<ROWS, 256, 0, stream>>>(xb, tmp, n2s + (size_t)l * D_MODEL, n2b + (size_t)l * D_MODEL);
    }

    cast_bf<<<(VOCAB * D_MODEL) / 1024, 256, 0, stream>>>(emb, embb, (size_t)VOCAB * D_MODEL);
    // head: NO XCD swizzle — bm-fastest order shares B panels via L3
    gemm256<0, 0><<<dim3((VOCAB / 256) * 16, 1), 512, 0, stream>>>(
        xb, D_MODEL, embb, D_MODEL, nullptr, d_out, VOCAB, D_MODEL);
}